// Round 13
// baseline (1877.089 us; speedup 1.0000x reference)
//
#include <hip/hip_runtime.h>

using u16 = unsigned short;
using u32 = unsigned int;

typedef __attribute__((ext_vector_type(8))) short short8;
typedef __attribute__((ext_vector_type(4))) float floatx4;

#define B_  4
#define NG_ 40962
#define NM_ 10242
#define E_  65536
#define NL_ 6

__device__ __forceinline__ float bf2f(u16 u) {
  union { float f; u32 i; } x; x.i = ((u32)u) << 16; return x.f;
}
__device__ __forceinline__ u16 f2bf(float f) {
  union { float f; u32 i; } x; x.f = f;
  u32 i = x.i;
  u32 r = (i + 0x7FFFu + ((i >> 16) & 1u)) >> 16;
  return (u16)r;
}
__device__ __forceinline__ float silu_f(float v) {
  float c = fminf(fmaxf(v, -88.f), 88.f);
  return c / (1.f + __expf(-c));
}
// no-clamp silu for bounded inputs (combine): exp(-v)=inf -> result 0, no NaN
__device__ __forceinline__ float silu_fast(float v) {
  return v / (1.f + __expf(-v));
}
__device__ __forceinline__ float satf(float v) {
  return fminf(fmaxf(v, -65504.f), 65504.f);
}
__device__ __forceinline__ float rdf(const void* p, long i, int flg) {
  return flg ? bf2f(((const u16*)p)[i]) : ((const float*)p)[i];
}

// ---------------- dtype detect ---------------------------------------------------------------
__global__ void detect_k(const u32* __restrict__ gg, int* __restrict__ flag) {
  if (threadIdx.x == 0) *flag = (gg[0] == 0x3F800000u) ? 0 : 1;
}

// ---------------- canonicalize one array to f32 ----------------------------------------------
__global__ __launch_bounds__(256) void cvt_k(const void* __restrict__ src, float* __restrict__ dst,
                                             long n, const int* __restrict__ flag) {
  int flg = *flag;
  long i = (long)blockIdx.x * 256 + threadIdx.x;
  if (i < n) dst[i] = rdf(src, i, flg);
}

// ---------------- canonicalize many small arrays ---------------------------------------------
struct CvtMany {
  const void* src[32];
  long soff[32];
  int off[32];
  int n[32];
  int cnt;
  float* dstbase;
  const int* flag;
};
__global__ __launch_bounds__(256) void cvt_many_k(CvtMany cm) {
  int e = blockIdx.y;
  if (e >= cm.cnt) return;
  int flg = *cm.flag;
  int i = blockIdx.x * 256 + threadIdx.x;
  if (i < cm.n[e]) cm.dstbase[cm.off[e] + i] = rdf(cm.src[e], cm.soff[e] + i, flg);
}

// ---------------- weight transpose -----------------------------------------------------------
__global__ void transpose_k(const void* __restrict__ src, u16* __restrict__ dst,
                            int K, int Kpad, long smat, long dmat, long soff,
                            const int* __restrict__ flag) {
  int flg = *flag;
  long l = blockIdx.z;
  int idx = blockIdx.x * 256 + threadIdx.x;
  int n = idx / Kpad;
  int k = idx - n * Kpad;
  if (n < 256)
    dst[l * dmat + (long)n * Kpad + k] =
        (k < K) ? f2bf(rdf(src, soff + l * smat + (long)k * 256 + n, flg)) : (u16)0;
}

// ---------------- zero helpers ---------------------------------------------------------------
__global__ __launch_bounds__(256) void zero_f32_k(float* __restrict__ p, long n4) {
  long i = (long)blockIdx.x * 256 + threadIdx.x;
  if (i < n4) ((float4*)p)[i] = (float4){0.f, 0.f, 0.f, 0.f};
}
__global__ __launch_bounds__(256) void zero_i32_k(int* __restrict__ p, int n) {
  int i = blockIdx.x * 256 + threadIdx.x;
  if (i < n) p[i] = 0;
}

// ---------------- CSR build (by destination) -------------------------------------------------
__global__ __launch_bounds__(256) void deg_count_k(const int* __restrict__ edst, int* __restrict__ deg) {
  int e = blockIdx.x * 256 + threadIdx.x;
  if (e < E_) atomicAdd(&deg[edst[e]], 1);
}
__global__ __launch_bounds__(256) void scan_k(const int* __restrict__ deg, int* __restrict__ off,
                                              int* __restrict__ pos) {
  __shared__ int tot[256];
  __shared__ int pre[257];
  const int CH = (NM_ + 255) / 256;
  int t = threadIdx.x;
  int base = t * CH;
  int s = 0;
  for (int i = 0; i < CH; i++) {
    int idx = base + i;
    if (idx < NM_) s += deg[idx];
  }
  tot[t] = s;
  __syncthreads();
  if (t == 0) {
    int acc = 0;
    for (int i = 0; i < 256; i++) { pre[i] = acc; acc += tot[i]; }
    pre[256] = acc;
  }
  __syncthreads();
  int acc = pre[t];
  for (int i = 0; i < CH; i++) {
    int idx = base + i;
    if (idx < NM_) { off[idx] = acc; pos[idx] = acc; acc += deg[idx]; }
  }
  if (t == 0) off[NM_] = pre[256];
}
__global__ __launch_bounds__(256) void csr_fill_k(const int* __restrict__ edst,
                                                  int* __restrict__ pos, int* __restrict__ ecsr) {
  int e = blockIdx.x * 256 + threadIdx.x;
  if (e < E_) {
    int p = atomicAdd(&pos[edst[e]], 1);
    ecsr[p] = e;
  }
}
__global__ __launch_bounds__(256) void srcs_k(const int* __restrict__ esrc,
                                              const int* __restrict__ ecsr, int* __restrict__ srcs) {
  int p = blockIdx.x * 256 + threadIdx.x;
  if (p < E_) srcs[p] = esrc[ecsr[p]];
}

// ---------------- per-layer: eaW_csr[p][c] = ea[ecsr[p]] . wbot[:,c] + bias[c] (bf16) --------
__global__ __launch_bounds__(256) void eaw_k(const float* __restrict__ ea,
                                             const int* __restrict__ ecsr,
                                             const float* __restrict__ wbot,
                                             const float* __restrict__ bias,
                                             u16* __restrict__ eaW) {
  int p = blockIdx.x, c = threadIdx.x;
  int e = ecsr[p];
  float4 v = *(const float4*)(ea + (long)e * 4);
  float val = v.x * wbot[c] + v.y * wbot[256 + c] + v.z * wbot[512 + c] + v.w * wbot[768 + c] + bias[c];
  eaW[(long)p * 256 + c] = f2bf(val);
}

// ---------------- grid encoder LN stats ------------------------------------------------------
__global__ __launch_bounds__(256) void grid_stats_k(const float* __restrict__ gin,
                                                    const float* __restrict__ w1,
                                                    const float* __restrict__ b1,
                                                    float* __restrict__ stats, int M) {
  int row = blockIdx.x * 4 + (threadIdx.x >> 6);
  int lane = threadIdx.x & 63;
  if (row >= M) return;
  float in0 = gin[(long)row * 2], in1 = gin[(long)row * 2 + 1];
  float s = 0.f, s2 = 0.f;
  #pragma unroll
  for (int j = 0; j < 4; j++) {
    int c = lane * 4 + j;
    float x = in0 * w1[c] + in1 * w1[256 + c] + b1[c];
    s += x; s2 += x * x;
  }
  #pragma unroll
  for (int o = 1; o < 64; o <<= 1) { s += __shfl_xor(s, o); s2 += __shfl_xor(s2, o); }
  if (lane == 0) {
    float mu = s * (1.f / 256.f);
    float var = fmaxf(s2 * (1.f / 256.f) - mu * mu, 0.f);
    stats[row * 2] = mu;
    stats[row * 2 + 1] = rsqrtf(var + 1e-5f);
  }
}

// ---------------- g2m pooling (single batch) -------------------------------------------------
__global__ __launch_bounds__(256) void g2m_b_k(const u16* __restrict__ gpb, const int* __restrict__ idx,
                                               const float* __restrict__ wts, u16* __restrict__ outb) {
  int m = blockIdx.x, c = threadIdx.x;
  float a = 0.f;
  #pragma unroll 4
  for (int k = 0; k < 16; k++) {
    int gi = idx[m * 16 + k];
    a += wts[m * 16 + k] * bf2f(gpb[(long)gi * 256 + c]);
  }
  outb[(long)m * 256 + c] = f2bf(a);
}

// ---------------- edge combine (CSR): U f32, V bf16, eaW bf16 CSR-ordered --------------------
__global__ __launch_bounds__(256) void edge_combine_csr_k(
    const float* __restrict__ U, const u16* __restrict__ V,
    const u16* __restrict__ eaW,
    const float* __restrict__ g, const float* __restrict__ beta,
    const int* __restrict__ srcs, const int* __restrict__ off,
    float* __restrict__ agg) {
  long gid = (long)blockIdx.x * 4 + (threadIdx.x >> 6);
  int lane = threadIdx.x & 63;
  int b = (int)(gid / NM_);
  int n = (int)(gid - (long)b * NM_);
  int c0 = lane * 4;

  float4 uu = *(const float4*)(U + gid * 256 + c0);
  float gc[4], bc[4];
  #pragma unroll
  for (int j = 0; j < 4; j++) { gc[j] = g[c0 + j]; bc[j] = beta[c0 + j]; }

  float a0 = 0.f, a1 = 0.f, a2 = 0.f, a3 = 0.f;
  const u16* Vb = V + (long)b * NM_ * 256;
  int e0 = off[n], e1 = off[n + 1];
  for (int i = e0; i < e1; i++) {
    int sn = srcs[i];
    union { uint2 u; u16 h[4]; } vv;
    vv.u = *(const uint2*)(Vb + (long)sn * 256 + c0);
    union { uint2 u; u16 h[4]; } ew;
    ew.u = *(const uint2*)(eaW + (long)i * 256 + c0);
    float m0 = uu.x + bf2f(vv.h[0]) + bf2f(ew.h[0]);
    float m1 = uu.y + bf2f(vv.h[1]) + bf2f(ew.h[1]);
    float m2 = uu.z + bf2f(vv.h[2]) + bf2f(ew.h[2]);
    float m3 = uu.w + bf2f(vv.h[3]) + bf2f(ew.h[3]);
    float s = m0 + m1 + m2 + m3;
    float s2 = m0 * m0 + m1 * m1 + m2 * m2 + m3 * m3;
    #pragma unroll
    for (int o = 1; o < 64; o <<= 1) { s += __shfl_xor(s, o); s2 += __shfl_xor(s2, o); }
    float mu = s * (1.f / 256.f);
    float var = fmaxf(s2 * (1.f / 256.f) - mu * mu, 0.f);
    float rs = rsqrtf(var + 1e-5f);
    a0 += silu_fast((m0 - mu) * rs * gc[0] + bc[0]);
    a1 += silu_fast((m1 - mu) * rs * gc[1] + bc[1]);
    a2 += silu_fast((m2 - mu) * rs * gc[2] + bc[2]);
    a3 += silu_fast((m3 - mu) * rs * gc[3] + bc[3]);
  }
  *(float4*)(agg + gid * 256 + c0) = (float4){a0, a1, a2, a3};
}

// ---------------- the MFMA GEMM template -----------------------------------------------------
enum { A_DIRECT = 0, A_NODE1 = 2, A_GRID = 3, A_COMB = 4, A_M2G = 5 };
enum { E_STORE = 0, E_STOREF = 1, E_STOREH = 2, E_LN_STORE = 3, E_RESID = 4, E_LN_DEC = 5 };

struct GemmP {
  const u16* A;
  const u16* Axh;      // node1: x bf16 shadow
  const float* Aagg;   // node1: agg f32
  const u16* Wt;
  const float* bias;
  const float* g;
  const float* beta;
  u16* Y;
  float* Yf;
  float* xf32;
  u16* xb16;
  const float* mf;
  const float* dw2;
  const float* db2;
  float* out2;
  const float* gin;
  const float* gw1;
  const float* gb1;
  const float* gg;
  const float* gbe;
  const float* stats;
  const u16* xsh;
  const int* m2gi;
  const float* m2gw;
  long rowoff;
  int M, K, Kpad;
};

__device__ __forceinline__ void cvt8(const float* __restrict__ src, u16* __restrict__ dst) {
  float4 f0 = ((const float4*)src)[0];
  float4 f1 = ((const float4*)src)[1];
  dst[0] = f2bf(f0.x); dst[1] = f2bf(f0.y); dst[2] = f2bf(f0.z); dst[3] = f2bf(f0.w);
  dst[4] = f2bf(f1.x); dst[5] = f2bf(f1.y); dst[6] = f2bf(f1.z); dst[7] = f2bf(f1.w);
}

template <int AM, int EM>
__global__ __launch_bounds__(256, 2) void gemm_k(GemmP p) {
  __shared__ __align__(16) u16 Asm[64 * 40];
  __shared__ __align__(16) u16 Bsm[256 * 40];
  __shared__ float red[4 * 64 * 2];
  __shared__ float stats_sm[64][2];

  const int t = threadIdx.x;
  const int lane = t & 63, w = t >> 6;
  const int l15 = lane & 15, q = lane >> 4;
  const long blk = blockIdx.x;

  const int lr = t >> 2;
  const int c8 = (t & 3) * 8;
  const long gr_s = blk * 64 + lr;
  const bool rowv = (gr_s < p.M);

  int cmn = 0;
  if (AM == A_COMB) cmn = (int)(gr_s % NM_);
  float gin0 = 0.f, gin1 = 0.f, gmu = 0.f, grs = 0.f;
  if (AM == A_GRID && rowv) {
    long grow = p.rowoff + gr_s;
    gin0 = p.gin[grow * 2];
    gin1 = p.gin[grow * 2 + 1];
    gmu = p.stats[grow * 2];
    grs = p.stats[grow * 2 + 1];
  }
  long xrow[4];
  float gw4[4];
  if (AM == A_M2G && rowv) {
    int b = (int)(gr_s / NG_);
    int gn = (int)(gr_s - (long)b * NG_);
    #pragma unroll
    for (int s = 0; s < 4; s++) {
      xrow[s] = ((long)(b * NM_ + p.m2gi[gn * 4 + s])) * 256;
      gw4[s] = p.m2gw[gn * 4 + s];
    }
  }

  floatx4 acc[4][4];
  #pragma unroll
  for (int i = 0; i < 4; i++)
    #pragma unroll
    for (int j = 0; j < 4; j++) acc[i][j] = (floatx4){0.f, 0.f, 0.f, 0.f};

  const int nk = p.Kpad >> 5;
  for (int ks = 0; ks < nk; ks++) {
    const int k0 = ks << 5;
    const int kc = k0 + c8;

    union { uint4 v; u16 s[8]; } av;
    av.v = (uint4){0u, 0u, 0u, 0u};
    if (AM == A_DIRECT) {
      if (rowv) av.v = *(const uint4*)(p.A + gr_s * (long)p.K + kc);
    } else if (AM == A_NODE1) {
      if (rowv) {
        if (kc < 256) av.v = *(const uint4*)(p.Axh + gr_s * 256 + kc);
        else          cvt8(p.Aagg + gr_s * 256 + (kc - 256), av.s);
      }
    } else if (AM == A_COMB) {
      if (rowv) {
        if (kc < 256) {
          av.v = *(const uint4*)(p.A + gr_s * 256 + kc);
        } else {
          #pragma unroll
          for (int j = 0; j < 8; j++) {
            int c = kc - 256 + j;
            av.s[j] = (c < 3) ? f2bf(p.mf[(long)cmn * 3 + c]) : (u16)0;
          }
        }
      }
    } else if (AM == A_M2G) {
      if (rowv) {
        float a8[8] = {0.f, 0.f, 0.f, 0.f, 0.f, 0.f, 0.f, 0.f};
        #pragma unroll
        for (int s = 0; s < 4; s++) {
          union { uint4 v; u16 h[8]; } xv;
          xv.v = *(const uint4*)(p.xsh + xrow[s] + kc);
          #pragma unroll
          for (int j = 0; j < 8; j++) a8[j] += gw4[s] * bf2f(xv.h[j]);
        }
        #pragma unroll
        for (int j = 0; j < 8; j++) av.s[j] = f2bf(a8[j]);
      }
    } else { // A_GRID
      if (rowv) {
        #pragma unroll
        for (int j = 0; j < 8; j++) {
          int c = kc + j;
          float tv = gin0 * p.gw1[c] + gin1 * p.gw1[256 + c] + p.gb1[c];
          float v = (tv - gmu) * grs * p.gg[c] + p.gbe[c];
          av.s[j] = f2bf(silu_f(v));
        }
      }
    }

    __syncthreads();
    *(uint4*)(Asm + lr * 40 + c8) = av.v;
    {
      const uint4* wp = (const uint4*)(p.Wt + (long)t * p.Kpad + k0);
      uint4 b0 = wp[0], b1 = wp[1], b2 = wp[2], b3 = wp[3];
      uint4* bs = (uint4*)(Bsm + t * 40);
      bs[0] = b0; bs[1] = b1; bs[2] = b2; bs[3] = b3;
    }
    __syncthreads();

    short8 af[4], bf[4];
    #pragma unroll
    for (int i = 0; i < 4; i++)
      af[i] = *(const short8*)(Asm + (i * 16 + l15) * 40 + q * 8);
    #pragma unroll
    for (int j = 0; j < 4; j++)
      bf[j] = *(const short8*)(Bsm + (w * 64 + j * 16 + l15) * 40 + q * 8);
    #pragma unroll
    for (int i = 0; i < 4; i++)
      #pragma unroll
      for (int j = 0; j < 4; j++)
        acc[i][j] = __builtin_amdgcn_mfma_f32_16x16x32_bf16(af[i], bf[j], acc[i][j], 0, 0, 0);
  }

  // ================= epilogue =================
  const int colb = w * 64 + l15;
  float bcol[4];
  #pragma unroll
  for (int j = 0; j < 4; j++) bcol[j] = p.bias ? p.bias[colb + j * 16] : 0.f;

  if (EM == E_STORE || EM == E_STOREF || EM == E_STOREH || EM == E_RESID) {
    #pragma unroll
    for (int i = 0; i < 4; i++) {
      #pragma unroll
      for (int r = 0; r < 4; r++) {
        long gr = blk * 64 + i * 16 + q * 4 + r;
        if (gr >= p.M) continue;
        long rowo = gr * 256 + colb;
        #pragma unroll
        for (int j = 0; j < 4; j++) {
          float v = acc[i][j][r] + bcol[j];
          long o = rowo + j * 16;
          if (EM == E_STORE || EM == E_STOREH) {
            p.Y[o] = f2bf(v);
          } else if (EM == E_STOREF) {
            p.Yf[o] = v;
          } else {
            float nv = satf(p.xf32[o] + v);
            p.xf32[o] = nv;
            p.xb16[o] = f2bf(nv);
          }
        }
      }
    }
    return;
  }

  // ---- LN: bias + row sums via 16-lane shuffle; cross-wave via 2 KB red ----
  #pragma unroll
  for (int i = 0; i < 4; i++) {
    #pragma unroll
    for (int r = 0; r < 4; r++) {
      float s = 0.f, s2 = 0.f;
      #pragma unroll
      for (int j = 0; j < 4; j++) {
        float v = satf(acc[i][j][r] + bcol[j]);
        acc[i][j][r] = v;
        s += v; s2 += v * v;
      }
      #pragma unroll
      for (int o = 1; o < 16; o <<= 1) { s += __shfl_xor(s, o); s2 += __shfl_xor(s2, o); }
      if (l15 == 0) {
        int ml = i * 16 + q * 4 + r;
        red[w * 128 + ml * 2]     = s;
        red[w * 128 + ml * 2 + 1] = s2;
      }
    }
  }
  __syncthreads();

  if (t < 64) {
    float s  = red[t * 2]     + red[128 + t * 2]     + red[256 + t * 2]     + red[384 + t * 2];
    float s2 = red[t * 2 + 1] + red[128 + t * 2 + 1] + red[256 + t * 2 + 1] + red[384 + t * 2 + 1];
    float mu = s * (1.f / 256.f);
    float var = fmaxf(s2 * (1.f / 256.f) - mu * mu, 0.f);
    stats_sm[t][0] = mu;
    stats_sm[t][1] = rsqrtf(var + 1e-5f);
  }
  __syncthreads();

  float gcol[4], becol[4];
  #pragma unroll
  for (int j = 0; j < 4; j++) { gcol[j] = p.g[colb + j * 16]; becol[j] = p.beta[colb + j * 16]; }

  if (EM == E_LN_STORE) {
    #pragma unroll
    for (int i = 0; i < 4; i++) {
      #pragma unroll
      for (int r = 0; r < 4; r++) {
        int ml = i * 16 + q * 4 + r;
        long gr = blk * 64 + ml;
        if (gr >= p.M) continue;
        float mu = stats_sm[ml][0], rs = stats_sm[ml][1];
        long rowo = gr * 256 + colb;
        #pragma unroll
        for (int j = 0; j < 4; j++) {
          float v = (acc[i][j][r] - mu) * rs * gcol[j] + becol[j];
          p.Y[rowo + j * 16] = f2bf(silu_f(v));
        }
      }
    }
  } else { // E_LN_DEC
    #pragma unroll
    for (int i = 0; i < 4; i++) {
      #pragma unroll
      for (int r = 0; r < 4; r++) {
        int ml = i * 16 + q * 4 + r;
        float mu = stats_sm[ml][0], rs = stats_sm[ml][1];
        float d0 = 0.f, d1 = 0.f;
        #pragma unroll
        for (int j = 0; j < 4; j++) {
          int col = colb + j * 16;
          float v = silu_f((acc[i][j][r] - mu) * rs * gcol[j] + becol[j]);
          d0 += v * p.dw2[col * 2];
          d1 += v * p.dw2[col * 2 + 1];
        }
        #pragma unroll
        for (int o = 1; o < 16; o <<= 1) { d0 += __shfl_xor(d0, o); d1 += __shfl_xor(d1, o); }
        if (l15 == 0) {
          red[w * 128 + ml * 2]     = d0;
          red[w * 128 + ml * 2 + 1] = d1;
        }
      }
    }
    __syncthreads();
    if (t < 64) {
      long gr = blk * 64 + t;
      if (gr < p.M) {
        float y0 = red[t * 2]     + red[128 + t * 2]     + red[256 + t * 2]     + red[384 + t * 2];
        float y1 = red[t * 2 + 1] + red[128 + t * 2 + 1] + red[256 + t * 2 + 1] + red[384 + t * 2 + 1];
        p.out2[gr * 2]     = y0 + p.db2[0];
        p.out2[gr * 2 + 1] = y1 + p.db2[1];
      }
    }
  }
}

// =================================================================================================
extern "C" void kernel_launch(void* const* d_in, const int* in_sizes, int n_in,
                              void* d_out, int out_size, void* d_ws, size_t ws_size,
                              hipStream_t stream) {
  const void* grid_input    = d_in[0];
  const void* mesh_features = d_in[1];
  const void* edge_attr     = d_in[2];
  const void* g2m_w         = d_in[3];
  const void* m2g_w         = d_in[4];
  const int* edge_index     = (const int*)d_in[5];
  const int* g2m_i          = (const int*)d_in[6];
  const int* m2g_i          = (const int*)d_in[7];
  const void* grid_w1 = d_in[8];
  const void* grid_b1 = d_in[9];
  const void* grid_g  = d_in[10];
  const void* grid_be = d_in[11];
  const void* grid_w2 = d_in[12];
  const void* grid_b2 = d_in[13];
  const void* comb_w1 = d_in[14];
  const void* comb_b1 = d_in[15];
  const void* comb_g  = d_in[16];
  const void* comb_be = d_in[17];
  const void* comb_w2 = d_in[18];
  const void* comb_b2 = d_in[19];
  const void* edge_w  = d_in[20];
  const void* edge_b  = d_in[21];
  const void* edge_g  = d_in[22];
  const void* edge_be = d_in[23];
  const void* node_w1 = d_in[24];
  const void* node_b1 = d_in[25];
  const void* node_g  = d_in[26];
  const void* node_be = d_in[27];
  const void* node_w2 = d_in[28];
  const void* node_b2 = d_in[29];
  const void* dec_w1  = d_in[30];
  const void* dec_b1  = d_in[31];
  const void* dec_g   = d_in[32];
  const void* dec_be  = d_in[33];
  const void* dec_w2  = d_in[34];
  const void* dec_b2  = d_in[35];
  (void)in_sizes; (void)n_in; (void)out_size; (void)ws_size;

  const long BNG = (long)B_ * NG_;
  const long BNM = (long)B_ * NM_;

  char* ws = (char*)d_ws;
  size_t off = 0;
  auto al = [&](size_t n) -> char* {
    char* pp = ws + off;
    off += (n + 255) & ~(size_t)255;
    return pp;
  };

  int* dflag = (int*)al(256);
  u16* wt_grid_w2 = (u16*)al(256 * 256 * 2);
  u16* wt_comb_w1 = (u16*)al(256 * 288 * 2);
  u16* wt_comb_w2 = (u16*)al(256 * 256 * 2);
  u16* wt_dec_w1  = (u16*)al(256 * 256 * 2);
  u16* wt_etop    = (u16*)al((size_t)NL_ * 256 * 256 * 2);
  u16* wt_emid    = (u16*)al((size_t)NL_ * 256 * 256 * 2);
  u16* wt_node1   = (u16*)al((size_t)NL_ * 256 * 512 * 2);
  u16* wt_node2   = (u16*)al((size_t)NL_ * 256 * 256 * 2);
  float* c_gin  = (float*)al((size_t)BNG * 2 * 4);
  float* c_mf   = (float*)al((size_t)NM_ * 3 * 4);
  float* c_ea   = (float*)al((size_t)E_ * 4 * 4);
  float* c_g2mw = (float*)al((size_t)NM_ * 16 * 4);
  float* c_m2gw = (float*)al((size_t)NG_ * 4 * 4);
  float* varena = (float*)al(24576 * 4);
  float* gstats = (float*)al((size_t)BNG * 2 * 4);
  int* deg  = (int*)al((size_t)NM_ * 4);
  int* offb = (int*)al((size_t)(NM_ + 1) * 4);
  int* posb = (int*)al((size_t)NM_ * 4);
  int* ecsr = (int*)al((size_t)E_ * 4);
  int* srcs = (int*)al((size_t)E_ * 4);
  u16* eaW  = (u16*)al((size_t)E_ * 256 * 2);   // 33.5 MB, CSR-ordered
  // region A (42 MB): gp_b/t2 (bf16) and U (f32)
  char* regA = al((size_t)BNM * 256 * 4);
  u16* gp_b   = (u16*)regA;
  u16* t2     = (u16*)regA;
  float* Uf   = (float*)regA;
  // region B (42 MB): pooled (bf16) then agg (f32)
  char* regB = al((size_t)BNM * 256 * 4);
  u16* pooled = (u16*)regB;
  float* agg  = (float*)regB;
  float* xf32 = (float*)al((size_t)BNM * 256 * 4);
  u16* xb16   = (u16*)al((size_t)BNM * 256 * 2);
  u16* Vh     = (u16*)al((size_t)BNM * 256 * 2);

  const int O_GB1 = 0, O_GG = 256, O_GBE = 512, O_GB2 = 768;
  const int O_CB1 = 1024, O_CG = 1280, O_CBE = 1536, O_CB2 = 1792;
  const int O_DB1 = 2048, O_DG = 2304, O_DBE = 2560, O_DB2 = 2816, O_DW2 = 2880;
  const int O_EB = 3584, O_EG = 5120, O_EBE = 6656;
  const int O_NB1 = 8192, O_NG = 9728, O_NBE = 11264, O_NB2 = 12800;
  const int O_GW1 = 14336;
  const int O_WBOT = 16384;

  detect_k<<<dim3(1), 64, 0, stream>>>((const u32*)grid_g, dflag);
  cvt_k<<<dim3((int)((BNG * 2 + 255) / 256)), 256, 0, stream>>>(grid_input, c_gin, BNG * 2, dflag);
  cvt_k<<<dim3((NM_ * 3 + 255) / 256), 256, 0, stream>>>(mesh_features, c_mf, (long)NM_ * 3, dflag);
  cvt_k<<<dim3((E_ * 4 + 255) / 256), 256, 0, stream>>>(edge_attr, c_ea, (long)E_ * 4, dflag);
  cvt_k<<<dim3((NM_ * 16 + 255) / 256), 256, 0, stream>>>(g2m_w, c_g2mw, (long)NM_ * 16, dflag);
  cvt_k<<<dim3((NG_ * 4 + 255) / 256), 256, 0, stream>>>(m2g_w, c_m2gw, (long)NG_ * 4, dflag);
  {
    CvtMany cm{};
    cm.dstbase = varena; cm.flag = dflag;
    int i = 0;
    auto add = [&](const void* s, long so, int o, int n) {
      cm.src[i] = s; cm.soff[i] = so; cm.off[i] = o; cm.n[i] = n; i++;
    };
    add(grid_b1, 0, O_GB1, 256); add(grid_g, 0, O_GG, 256); add(grid_be, 0, O_GBE, 256); add(grid_b2, 0, O_GB2, 256);
    add(comb_b1, 0, O_CB1, 256); add(comb_g, 0, O_CG, 256); add(comb_be, 0, O_CBE, 256); add(comb_b2, 0, O_CB2, 256);
    add(dec_b1, 0, O_DB1, 256);  add(dec_g, 0, O_DG, 256);  add(dec_be, 0, O_DBE, 256);  add(dec_b2, 0, O_DB2, 2);
    add(dec_w2, 0, O_DW2, 512);
    add(edge_b, 0, O_EB, NL_ * 256); add(edge_g, 0, O_EG, NL_ * 256); add(edge_be, 0, O_EBE, NL_ * 256);
    add(node_b1, 0, O_NB1, NL_ * 256); add(node_g, 0, O_NG, NL_ * 256); add(node_be, 0, O_NBE, NL_ * 256);
    add(node_b2, 0, O_NB2, NL_ * 256);
    add(grid_w1, 0, O_GW1, 512);
    for (int l = 0; l < NL_; l++)
      add(edge_w, (long)l * 516 * 256 + 512 * 256, O_WBOT + l * 1024, 1024);
    cm.cnt = i;
    cvt_many_k<<<dim3(6, cm.cnt), 256, 0, stream>>>(cm);
  }

  transpose_k<<<dim3(256, 1, 1), 256, 0, stream>>>(grid_w2, wt_grid_w2, 256, 256, 0, 0, 0, dflag);
  transpose_k<<<dim3(288, 1, 1), 256, 0, stream>>>(comb_w1, wt_comb_w1, 259, 288, 0, 0, 0, dflag);
  transpose_k<<<dim3(256, 1, 1), 256, 0, stream>>>(comb_w2, wt_comb_w2, 256, 256, 0, 0, 0, dflag);
  transpose_k<<<dim3(256, 1, 1), 256, 0, stream>>>(dec_w1,  wt_dec_w1,  256, 256, 0, 0, 0, dflag);
  transpose_k<<<dim3(256, 1, NL_), 256, 0, stream>>>(edge_w, wt_etop, 256, 256, (long)516 * 256, (long)256 * 256, 0, dflag);
  transpose_k<<<dim3(256, 1, NL_), 256, 0, stream>>>(edge_w, wt_emid, 256, 256, (long)516 * 256, (long)256 * 256, (long)256 * 256, dflag);
  transpose_k<<<dim3(512, 1, NL_), 256, 0, stream>>>(node_w1, wt_node1, 512, 512, (long)512 * 256, (long)256 * 512, 0, dflag);
  transpose_k<<<dim3(256, 1, NL_), 256, 0, stream>>>(node_w2, wt_node2, 256, 256, (long)256 * 256, (long)256 * 256, 0, dflag);

  // ---- CSR build (by dst) + CSR-ordered src gather ----
  zero_i32_k<<<dim3((NM_ + 255) / 256), 256, 0, stream>>>(deg, NM_);
  deg_count_k<<<dim3(E_ / 256), 256, 0, stream>>>(edge_index + E_, deg);
  scan_k<<<dim3(1), 256, 0, stream>>>(deg, offb, posb);
  csr_fill_k<<<dim3(E_ / 256), 256, 0, stream>>>(edge_index + E_, posb, ecsr);
  srcs_k<<<dim3(E_ / 256), 256, 0, stream>>>(edge_index, ecsr, srcs);

  grid_stats_k<<<dim3((int)(BNG / 4)), 256, 0, stream>>>(c_gin, varena + O_GW1, varena + O_GB1, gstats, (int)BNG);

  // ---- grid encoder + g2m pooling, streamed per batch ----
  for (int b = 0; b < B_; b++) {
    GemmP p{}; p.Wt = wt_grid_w2; p.bias = varena + O_GB2; p.Y = gp_b;
    p.gin = c_gin; p.gw1 = varena + O_GW1; p.gb1 = varena + O_GB1;
    p.gg = varena + O_GG; p.gbe = varena + O_GBE;
    p.stats = gstats; p.rowoff = (long)b * NG_;
    p.M = NG_; p.K = 256; p.Kpad = 256;
    gemm_k<A_GRID, E_STORE><<<dim3((NG_ + 63) / 64), 256, 0, stream>>>(p);
    g2m_b_k<<<dim3(NM_), 256, 0, stream>>>(gp_b, g2m_i, c_g2mw, pooled + (long)b * NM_ * 256);
  }

  // ---- comb MLP ----
  {
    GemmP p{}; p.A = pooled; p.mf = c_mf; p.Wt = wt_comb_w1; p.bias = varena + O_CB1;
    p.g = varena + O_CG; p.beta = varena + O_CBE; p.Y = t2; p.M = (int)BNM; p.K = 259; p.Kpad = 288;
    gemm_k<A_COMB, E_LN_STORE><<<dim3((int)((BNM + 63) / 64)), 256, 0, stream>>>(p);
  }
  const long n4 = BNM * 256 / 4;
  zero_f32_k<<<dim3((int)((n4 + 255) / 256)), 256, 0, stream>>>(xf32, n4);
  {
    GemmP p{}; p.A = t2; p.Wt = wt_comb_w2; p.bias = varena + O_CB2;
    p.xf32 = xf32; p.xb16 = xb16;
    p.M = (int)BNM; p.K = 256; p.Kpad = 256;
    gemm_k<A_DIRECT, E_RESID><<<dim3((int)((BNM + 63) / 64)), 256, 0, stream>>>(p);
  }

  // ---- message-passing layers ----
  for (int l = 0; l < NL_; l++) {
    eaw_k<<<dim3(E_), 256, 0, stream>>>(c_ea, ecsr, varena + O_WBOT + l * 1024,
                                        varena + O_EB + l * 256, eaW);
    {
      GemmP p{}; p.A = xb16; p.Wt = wt_etop + (size_t)l * 256 * 256; p.Yf = Uf;
      p.M = (int)BNM; p.K = 256; p.Kpad = 256;
      gemm_k<A_DIRECT, E_STOREF><<<dim3((int)((BNM + 63) / 64)), 256, 0, stream>>>(p);
    }
    {
      GemmP p{}; p.A = xb16; p.Wt = wt_emid + (size_t)l * 256 * 256; p.Y = Vh;
      p.M = (int)BNM; p.K = 256; p.Kpad = 256;
      gemm_k<A_DIRECT, E_STOREH><<<dim3((int)((BNM + 63) / 64)), 256, 0, stream>>>(p);
    }
    edge_combine_csr_k<<<dim3((int)(BNM / 4)), 256, 0, stream>>>(
        Uf, Vh, eaW,
        varena + O_EG + l * 256, varena + O_EBE + l * 256,
        srcs, offb, agg);
    {
      GemmP p{}; p.Axh = xb16; p.Aagg = agg; p.Wt = wt_node1 + (size_t)l * 256 * 512;
      p.bias = varena + O_NB1 + l * 256; p.g = varena + O_NG + l * 256; p.beta = varena + O_NBE + l * 256;
      p.Y = t2; p.M = (int)BNM; p.K = 512; p.Kpad = 512;
      gemm_k<A_NODE1, E_LN_STORE><<<dim3((int)((BNM + 63) / 64)), 256, 0, stream>>>(p);
    }
    {
      GemmP p{}; p.A = t2; p.Wt = wt_node2 + (size_t)l * 256 * 256;
      p.bias = varena + O_NB2 + l * 256; p.xf32 = xf32; p.xb16 = xb16;
      p.M = (int)BNM; p.K = 256; p.Kpad = 256;
      gemm_k<A_DIRECT, E_RESID><<<dim3((int)((BNM + 63) / 64)), 256, 0, stream>>>(p);
    }
  }

  // ---- decoder: fused m2g gather staging, single launch; f32 output ----
  {
    GemmP p{}; p.Wt = wt_dec_w1; p.bias = varena + O_DB1;
    p.g = varena + O_DG; p.beta = varena + O_DBE;
    p.dw2 = varena + O_DW2; p.db2 = varena + O_DB2;
    p.out2 = (float*)d_out;
    p.xsh = xb16; p.m2gi = m2g_i; p.m2gw = c_m2gw;
    p.M = (int)BNG; p.K = 256; p.Kpad = 256;
    gemm_k<A_M2G, E_LN_DEC><<<dim3((int)((BNG + 63) / 64)), 256, 0, stream>>>(p);
  }
}

// Round 14
// 1778.560 us; speedup vs baseline: 1.0554x; 1.0554x over previous
//
#include <hip/hip_runtime.h>

using u16 = unsigned short;
using u32 = unsigned int;

typedef __attribute__((ext_vector_type(8))) short short8;
typedef __attribute__((ext_vector_type(4))) float floatx4;

#define B_  4
#define NG_ 40962
#define NM_ 10242
#define E_  65536
#define NL_ 6

__device__ __forceinline__ float bf2f(u16 u) {
  union { float f; u32 i; } x; x.i = ((u32)u) << 16; return x.f;
}
__device__ __forceinline__ u16 f2bf(float f) {
  union { float f; u32 i; } x; x.f = f;
  u32 i = x.i;
  u32 r = (i + 0x7FFFu + ((i >> 16) & 1u)) >> 16;
  return (u16)r;
}
__device__ __forceinline__ float silu_f(float v) {
  float c = fminf(fmaxf(v, -88.f), 88.f);
  return c / (1.f + __expf(-c));
}
__device__ __forceinline__ float silu_fast(float v) {
  return v / (1.f + __expf(-v));
}
__device__ __forceinline__ float satf(float v) {
  return fminf(fmaxf(v, -65504.f), 65504.f);
}
__device__ __forceinline__ float rdf(const void* p, long i, int flg) {
  return flg ? bf2f(((const u16*)p)[i]) : ((const float*)p)[i];
}

// ---------------- dtype detect ---------------------------------------------------------------
__global__ void detect_k(const u32* __restrict__ gg, int* __restrict__ flag) {
  if (threadIdx.x == 0) *flag = (gg[0] == 0x3F800000u) ? 0 : 1;
}

// ---------------- canonicalize one array to f32 ----------------------------------------------
__global__ __launch_bounds__(256) void cvt_k(const void* __restrict__ src, float* __restrict__ dst,
                                             long n, const int* __restrict__ flag) {
  int flg = *flag;
  long i = (long)blockIdx.x * 256 + threadIdx.x;
  if (i < n) dst[i] = rdf(src, i, flg);
}

// ---------------- canonicalize many small arrays ---------------------------------------------
struct CvtMany {
  const void* src[32];
  long soff[32];
  int off[32];
  int n[32];
  int cnt;
  float* dstbase;
  const int* flag;
};
__global__ __launch_bounds__(256) void cvt_many_k(CvtMany cm) {
  int e = blockIdx.y;
  if (e >= cm.cnt) return;
  int flg = *cm.flag;
  int i = blockIdx.x * 256 + threadIdx.x;
  if (i < cm.n[e]) cm.dstbase[cm.off[e] + i] = rdf(cm.src[e], cm.soff[e] + i, flg);
}

// ---------------- weight transpose -----------------------------------------------------------
__global__ void transpose_k(const void* __restrict__ src, u16* __restrict__ dst,
                            int K, int Kpad, long smat, long dmat, long soff,
                            const int* __restrict__ flag) {
  int flg = *flag;
  long l = blockIdx.z;
  int idx = blockIdx.x * 256 + threadIdx.x;
  int n = idx / Kpad;
  int k = idx - n * Kpad;
  if (n < 256)
    dst[l * dmat + (long)n * Kpad + k] =
        (k < K) ? f2bf(rdf(src, soff + l * smat + (long)k * 256 + n, flg)) : (u16)0;
}

// ---------------- zero helpers ---------------------------------------------------------------
__global__ __launch_bounds__(256) void zero_f32_k(float* __restrict__ p, long n4) {
  long i = (long)blockIdx.x * 256 + threadIdx.x;
  if (i < n4) ((float4*)p)[i] = (float4){0.f, 0.f, 0.f, 0.f};
}
__global__ __launch_bounds__(256) void zero_i32_k(int* __restrict__ p, int n) {
  int i = blockIdx.x * 256 + threadIdx.x;
  if (i < n) p[i] = 0;
}

// ---------------- CSR build (by destination) -------------------------------------------------
__global__ __launch_bounds__(256) void deg_count_k(const int* __restrict__ edst, int* __restrict__ deg) {
  int e = blockIdx.x * 256 + threadIdx.x;
  if (e < E_) atomicAdd(&deg[edst[e]], 1);
}
__global__ __launch_bounds__(256) void scan_k(const int* __restrict__ deg, int* __restrict__ off,
                                              int* __restrict__ pos) {
  __shared__ int tot[256];
  __shared__ int pre[257];
  const int CH = (NM_ + 255) / 256;
  int t = threadIdx.x;
  int base = t * CH;
  int s = 0;
  for (int i = 0; i < CH; i++) {
    int idx = base + i;
    if (idx < NM_) s += deg[idx];
  }
  tot[t] = s;
  __syncthreads();
  if (t == 0) {
    int acc = 0;
    for (int i = 0; i < 256; i++) { pre[i] = acc; acc += tot[i]; }
    pre[256] = acc;
  }
  __syncthreads();
  int acc = pre[t];
  for (int i = 0; i < CH; i++) {
    int idx = base + i;
    if (idx < NM_) { off[idx] = acc; pos[idx] = acc; acc += deg[idx]; }
  }
  if (t == 0) off[NM_] = pre[256];
}
__global__ __launch_bounds__(256) void csr_fill_k(const int* __restrict__ edst,
                                                  int* __restrict__ pos, int* __restrict__ ecsr) {
  int e = blockIdx.x * 256 + threadIdx.x;
  if (e < E_) {
    int p = atomicAdd(&pos[edst[e]], 1);
    ecsr[p] = e;
  }
}
__global__ __launch_bounds__(256) void srcs_k(const int* __restrict__ esrc,
                                              const int* __restrict__ ecsr, int* __restrict__ srcs) {
  int p = blockIdx.x * 256 + threadIdx.x;
  if (p < E_) srcs[p] = esrc[ecsr[p]];
}

// ---------------- per-layer eaW (4 edges per block) ------------------------------------------
__global__ __launch_bounds__(256) void eaw_k(const float* __restrict__ ea,
                                             const int* __restrict__ ecsr,
                                             const float* __restrict__ wbot,
                                             const float* __restrict__ bias,
                                             u16* __restrict__ eaW) {
  int c = threadIdx.x;
  float w0 = wbot[c], w1 = wbot[256 + c], w2 = wbot[512 + c], w3 = wbot[768 + c], bi = bias[c];
  int p0 = blockIdx.x * 4;
  #pragma unroll
  for (int r = 0; r < 4; r++) {
    int p = p0 + r;
    int e = ecsr[p];
    float4 v = *(const float4*)(ea + (long)e * 4);
    eaW[(long)p * 256 + c] = f2bf(v.x * w0 + v.y * w1 + v.z * w2 + v.w * w3 + bi);
  }
}

// ---------------- grid encoder LN stats ------------------------------------------------------
__global__ __launch_bounds__(256) void grid_stats_k(const float* __restrict__ gin,
                                                    const float* __restrict__ w1,
                                                    const float* __restrict__ b1,
                                                    float* __restrict__ stats, int M) {
  int row = blockIdx.x * 4 + (threadIdx.x >> 6);
  int lane = threadIdx.x & 63;
  if (row >= M) return;
  float in0 = gin[(long)row * 2], in1 = gin[(long)row * 2 + 1];
  float s = 0.f, s2 = 0.f;
  #pragma unroll
  for (int j = 0; j < 4; j++) {
    int c = lane * 4 + j;
    float x = in0 * w1[c] + in1 * w1[256 + c] + b1[c];
    s += x; s2 += x * x;
  }
  #pragma unroll
  for (int o = 1; o < 64; o <<= 1) { s += __shfl_xor(s, o); s2 += __shfl_xor(s2, o); }
  if (lane == 0) {
    float mu = s * (1.f / 256.f);
    float var = fmaxf(s2 * (1.f / 256.f) - mu * mu, 0.f);
    stats[row * 2] = mu;
    stats[row * 2 + 1] = rsqrtf(var + 1e-5f);
  }
}

// ---------------- g2m pooling (single batch) -------------------------------------------------
__global__ __launch_bounds__(256) void g2m_b_k(const u16* __restrict__ gpb, const int* __restrict__ idx,
                                               const float* __restrict__ wts, u16* __restrict__ outb) {
  int m = blockIdx.x, c = threadIdx.x;
  float a = 0.f;
  #pragma unroll 4
  for (int k = 0; k < 16; k++) {
    int gi = idx[m * 16 + k];
    a += wts[m * 16 + k] * bf2f(gpb[(long)gi * 256 + c]);
  }
  outb[(long)m * 256 + c] = f2bf(a);
}

// ---------------- edge combine (CSR): one wave per (node, batch-pair) ------------------------
__global__ __launch_bounds__(256) void edge_combine_csr2_k(
    const float* __restrict__ U, const u16* __restrict__ V,
    const u16* __restrict__ eaW,
    const float* __restrict__ g, const float* __restrict__ beta,
    const int* __restrict__ srcs, const int* __restrict__ off,
    float* __restrict__ agg) {
  long gid = (long)blockIdx.x * 4 + (threadIdx.x >> 6);   // unit in [0, 2*NM)
  if (gid >= 2L * NM_) return;
  int lane = threadIdx.x & 63;
  int h = (int)(gid / NM_);            // 0 or 1
  int n = (int)(gid - (long)h * NM_);
  int b0 = 2 * h, b1 = 2 * h + 1;
  int c0 = lane * 4;

  float4 uu0 = *(const float4*)(U + ((long)b0 * NM_ + n) * 256 + c0);
  float4 uu1 = *(const float4*)(U + ((long)b1 * NM_ + n) * 256 + c0);
  float gc[4], bc[4];
  #pragma unroll
  for (int j = 0; j < 4; j++) { gc[j] = g[c0 + j]; bc[j] = beta[c0 + j]; }

  float A0[4] = {0.f, 0.f, 0.f, 0.f};
  float A1[4] = {0.f, 0.f, 0.f, 0.f};
  const u16* Vb0 = V + (long)b0 * NM_ * 256;
  const u16* Vb1 = V + (long)b1 * NM_ * 256;
  int e0 = off[n], e1 = off[n + 1];
  for (int i = e0; i < e1; i++) {
    int sn = srcs[i];
    union { uint2 u; u16 h4[4]; } ew, v0, v1;
    ew.u = *(const uint2*)(eaW + (long)i * 256 + c0);
    v0.u = *(const uint2*)(Vb0 + (long)sn * 256 + c0);
    v1.u = *(const uint2*)(Vb1 + (long)sn * 256 + c0);
    float m0[4], m1[4];
    float s0 = 0.f, q0 = 0.f, s1 = 0.f, q1 = 0.f;
    const float* up0 = (const float*)&uu0;
    const float* up1 = (const float*)&uu1;
    #pragma unroll
    for (int j = 0; j < 4; j++) {
      float e_ = bf2f(ew.h4[j]);
      float a = up0[j] + bf2f(v0.h4[j]) + e_;
      float b = up1[j] + bf2f(v1.h4[j]) + e_;
      m0[j] = a; m1[j] = b;
      s0 += a; q0 += a * a;
      s1 += b; q1 += b * b;
    }
    #pragma unroll
    for (int o = 1; o < 64; o <<= 1) {
      s0 += __shfl_xor(s0, o); q0 += __shfl_xor(q0, o);
      s1 += __shfl_xor(s1, o); q1 += __shfl_xor(q1, o);
    }
    float mu0 = s0 * (1.f / 256.f);
    float rs0 = rsqrtf(fmaxf(q0 * (1.f / 256.f) - mu0 * mu0, 0.f) + 1e-5f);
    float mu1 = s1 * (1.f / 256.f);
    float rs1 = rsqrtf(fmaxf(q1 * (1.f / 256.f) - mu1 * mu1, 0.f) + 1e-5f);
    #pragma unroll
    for (int j = 0; j < 4; j++) {
      A0[j] += silu_fast((m0[j] - mu0) * rs0 * gc[j] + bc[j]);
      A1[j] += silu_fast((m1[j] - mu1) * rs1 * gc[j] + bc[j]);
    }
  }
  *(float4*)(agg + ((long)b0 * NM_ + n) * 256 + c0) = (float4){A0[0], A0[1], A0[2], A0[3]};
  *(float4*)(agg + ((long)b1 * NM_ + n) * 256 + c0) = (float4){A1[0], A1[1], A1[2], A1[3]};
}

// ---------------- the MFMA GEMM template -----------------------------------------------------
enum { A_DIRECT = 0, A_NODE1 = 2, A_GRID = 3, A_COMB = 4, A_M2G = 5 };
enum { E_STORE = 0, E_STOREF = 1, E_STOREH = 2, E_LN_STORE = 3, E_RESID = 4, E_LN_DEC = 5, E_STORE_UV = 6 };

struct GemmP {
  const u16* A;
  const u16* Axh;      // node1: x bf16 shadow
  const float* Aagg;   // node1: agg f32
  const u16* Wt;
  const u16* Wt2;      // E_STORE_UV: second weight set (V)
  const float* bias;
  const float* g;
  const float* beta;
  u16* Y;
  float* Yf;
  float* xf32;
  u16* xb16;
  const float* mf;
  const float* dw2;
  const float* db2;
  float* out2;
  const float* gin;
  const float* gw1;
  const float* gb1;
  const float* gg;
  const float* gbe;
  const float* stats;
  const u16* xsh;
  const int* m2gi;
  const float* m2gw;
  long rowoff;
  int M, K, Kpad;
};

__device__ __forceinline__ void cvt8(const float* __restrict__ src, u16* __restrict__ dst) {
  float4 f0 = ((const float4*)src)[0];
  float4 f1 = ((const float4*)src)[1];
  dst[0] = f2bf(f0.x); dst[1] = f2bf(f0.y); dst[2] = f2bf(f0.z); dst[3] = f2bf(f0.w);
  dst[4] = f2bf(f1.x); dst[5] = f2bf(f1.y); dst[6] = f2bf(f1.z); dst[7] = f2bf(f1.w);
}

template <int AM, int EM>
__global__ __launch_bounds__(256, 2) void gemm_k(GemmP p) {
  __shared__ __align__(16) u16 Asm[64 * 40];
  __shared__ __align__(16) u16 Bsm[256 * 40];
  __shared__ float red[4 * 64 * 2];
  __shared__ float stats_sm[64][2];

  const int t = threadIdx.x;
  const int lane = t & 63, w = t >> 6;
  const int l15 = lane & 15, q = lane >> 4;
  const long blk = blockIdx.x;

  const int lr = t >> 2;
  const int c8 = (t & 3) * 8;
  const long gr_s = blk * 64 + lr;
  const bool rowv = (gr_s < p.M);

  const u16* Wt = p.Wt;
  if (EM == E_STORE_UV && blockIdx.y == 1) Wt = p.Wt2;

  int cmn = 0;
  if (AM == A_COMB) cmn = (int)(gr_s % NM_);
  float gin0 = 0.f, gin1 = 0.f, gmu = 0.f, grs = 0.f;
  if (AM == A_GRID && rowv) {
    long grow = p.rowoff + gr_s;
    gin0 = p.gin[grow * 2];
    gin1 = p.gin[grow * 2 + 1];
    gmu = p.stats[grow * 2];
    grs = p.stats[grow * 2 + 1];
  }
  long xrow[4];
  float gw4[4];
  if (AM == A_M2G && rowv) {
    int b = (int)(gr_s / NG_);
    int gn = (int)(gr_s - (long)b * NG_);
    #pragma unroll
    for (int s = 0; s < 4; s++) {
      xrow[s] = ((long)(b * NM_ + p.m2gi[gn * 4 + s])) * 256;
      gw4[s] = p.m2gw[gn * 4 + s];
    }
  }

  floatx4 acc[4][4];
  #pragma unroll
  for (int i = 0; i < 4; i++)
    #pragma unroll
    for (int j = 0; j < 4; j++) acc[i][j] = (floatx4){0.f, 0.f, 0.f, 0.f};

  const int nk = p.Kpad >> 5;
  for (int ks = 0; ks < nk; ks++) {
    const int k0 = ks << 5;
    const int kc = k0 + c8;

    union { uint4 v; u16 s[8]; } av;
    av.v = (uint4){0u, 0u, 0u, 0u};
    if (AM == A_DIRECT) {
      if (rowv) av.v = *(const uint4*)(p.A + gr_s * (long)p.K + kc);
    } else if (AM == A_NODE1) {
      if (rowv) {
        if (kc < 256) av.v = *(const uint4*)(p.Axh + gr_s * 256 + kc);
        else          cvt8(p.Aagg + gr_s * 256 + (kc - 256), av.s);
      }
    } else if (AM == A_COMB) {
      if (rowv) {
        if (kc < 256) {
          av.v = *(const uint4*)(p.A + gr_s * 256 + kc);
        } else {
          #pragma unroll
          for (int j = 0; j < 8; j++) {
            int c = kc - 256 + j;
            av.s[j] = (c < 3) ? f2bf(p.mf[(long)cmn * 3 + c]) : (u16)0;
          }
        }
      }
    } else if (AM == A_M2G) {
      if (rowv) {
        float a8[8] = {0.f, 0.f, 0.f, 0.f, 0.f, 0.f, 0.f, 0.f};
        #pragma unroll
        for (int s = 0; s < 4; s++) {
          union { uint4 v; u16 h[8]; } xv;
          xv.v = *(const uint4*)(p.xsh + xrow[s] + kc);
          #pragma unroll
          for (int j = 0; j < 8; j++) a8[j] += gw4[s] * bf2f(xv.h[j]);
        }
        #pragma unroll
        for (int j = 0; j < 8; j++) av.s[j] = f2bf(a8[j]);
      }
    } else { // A_GRID
      if (rowv) {
        #pragma unroll
        for (int j = 0; j < 8; j++) {
          int c = kc + j;
          float tv = gin0 * p.gw1[c] + gin1 * p.gw1[256 + c] + p.gb1[c];
          float v = (tv - gmu) * grs * p.gg[c] + p.gbe[c];
          av.s[j] = f2bf(silu_f(v));
        }
      }
    }

    __syncthreads();
    *(uint4*)(Asm + lr * 40 + c8) = av.v;
    {
      const uint4* wp = (const uint4*)(Wt + (long)t * p.Kpad + k0);
      uint4 b0 = wp[0], b1 = wp[1], b2 = wp[2], b3 = wp[3];
      uint4* bs = (uint4*)(Bsm + t * 40);
      bs[0] = b0; bs[1] = b1; bs[2] = b2; bs[3] = b3;
    }
    __syncthreads();

    short8 af[4], bf[4];
    #pragma unroll
    for (int i = 0; i < 4; i++)
      af[i] = *(const short8*)(Asm + (i * 16 + l15) * 40 + q * 8);
    #pragma unroll
    for (int j = 0; j < 4; j++)
      bf[j] = *(const short8*)(Bsm + (w * 64 + j * 16 + l15) * 40 + q * 8);
    #pragma unroll
    for (int i = 0; i < 4; i++)
      #pragma unroll
      for (int j = 0; j < 4; j++)
        acc[i][j] = __builtin_amdgcn_mfma_f32_16x16x32_bf16(af[i], bf[j], acc[i][j], 0, 0, 0);
  }

  // ================= epilogue =================
  const int colb = w * 64 + l15;
  float bcol[4];
  #pragma unroll
  for (int j = 0; j < 4; j++) bcol[j] = p.bias ? p.bias[colb + j * 16] : 0.f;

  if (EM == E_STORE || EM == E_STOREF || EM == E_STOREH || EM == E_RESID || EM == E_STORE_UV) {
    const bool isV = (EM == E_STORE_UV) && (blockIdx.y == 1);
    #pragma unroll
    for (int i = 0; i < 4; i++) {
      #pragma unroll
      for (int r = 0; r < 4; r++) {
        long gr = blk * 64 + i * 16 + q * 4 + r;
        if (gr >= p.M) continue;
        long rowo = gr * 256 + colb;
        #pragma unroll
        for (int j = 0; j < 4; j++) {
          float v = acc[i][j][r] + bcol[j];
          long o = rowo + j * 16;
          if (EM == E_STORE || EM == E_STOREH) {
            p.Y[o] = f2bf(v);
          } else if (EM == E_STOREF) {
            p.Yf[o] = v;
          } else if (EM == E_STORE_UV) {
            if (isV) p.Y[o] = f2bf(v);
            else     p.Yf[o] = v;
          } else {
            float nv = satf(p.xf32[o] + v);
            p.xf32[o] = nv;
            p.xb16[o] = f2bf(nv);
          }
        }
      }
    }
    return;
  }

  // ---- LN: bias + row sums via 16-lane shuffle; cross-wave via 2 KB red ----
  #pragma unroll
  for (int i = 0; i < 4; i++) {
    #pragma unroll
    for (int r = 0; r < 4; r++) {
      float s = 0.f, s2 = 0.f;
      #pragma unroll
      for (int j = 0; j < 4; j++) {
        float v = satf(acc[i][j][r] + bcol[j]);
        acc[i][j][r] = v;
        s += v; s2 += v * v;
      }
      #pragma unroll
      for (int o = 1; o < 16; o <<= 1) { s += __shfl_xor(s, o); s2 += __shfl_xor(s2, o); }
      if (l15 == 0) {
        int ml = i * 16 + q * 4 + r;
        red[w * 128 + ml * 2]     = s;
        red[w * 128 + ml * 2 + 1] = s2;
      }
    }
  }
  __syncthreads();

  if (t < 64) {
    float s  = red[t * 2]     + red[128 + t * 2]     + red[256 + t * 2]     + red[384 + t * 2];
    float s2 = red[t * 2 + 1] + red[128 + t * 2 + 1] + red[256 + t * 2 + 1] + red[384 + t * 2 + 1];
    float mu = s * (1.f / 256.f);
    float var = fmaxf(s2 * (1.f / 256.f) - mu * mu, 0.f);
    stats_sm[t][0] = mu;
    stats_sm[t][1] = rsqrtf(var + 1e-5f);
  }
  __syncthreads();

  float gcol[4], becol[4];
  #pragma unroll
  for (int j = 0; j < 4; j++) { gcol[j] = p.g[colb + j * 16]; becol[j] = p.beta[colb + j * 16]; }

  if (EM == E_LN_STORE) {
    #pragma unroll
    for (int i = 0; i < 4; i++) {
      #pragma unroll
      for (int r = 0; r < 4; r++) {
        int ml = i * 16 + q * 4 + r;
        long gr = blk * 64 + ml;
        if (gr >= p.M) continue;
        float mu = stats_sm[ml][0], rs = stats_sm[ml][1];
        long rowo = gr * 256 + colb;
        #pragma unroll
        for (int j = 0; j < 4; j++) {
          float v = (acc[i][j][r] - mu) * rs * gcol[j] + becol[j];
          p.Y[rowo + j * 16] = f2bf(silu_f(v));
        }
      }
    }
  } else { // E_LN_DEC
    #pragma unroll
    for (int i = 0; i < 4; i++) {
      #pragma unroll
      for (int r = 0; r < 4; r++) {
        int ml = i * 16 + q * 4 + r;
        float mu = stats_sm[ml][0], rs = stats_sm[ml][1];
        float d0 = 0.f, d1 = 0.f;
        #pragma unroll
        for (int j = 0; j < 4; j++) {
          int col = colb + j * 16;
          float v = silu_f((acc[i][j][r] - mu) * rs * gcol[j] + becol[j]);
          d0 += v * p.dw2[col * 2];
          d1 += v * p.dw2[col * 2 + 1];
        }
        #pragma unroll
        for (int o = 1; o < 16; o <<= 1) { d0 += __shfl_xor(d0, o); d1 += __shfl_xor(d1, o); }
        if (l15 == 0) {
          red[w * 128 + ml * 2]     = d0;
          red[w * 128 + ml * 2 + 1] = d1;
        }
      }
    }
    __syncthreads();
    if (t < 64) {
      long gr = blk * 64 + t;
      if (gr < p.M) {
        float y0 = red[t * 2]     + red[128 + t * 2]     + red[256 + t * 2]     + red[384 + t * 2];
        float y1 = red[t * 2 + 1] + red[128 + t * 2 + 1] + red[256 + t * 2 + 1] + red[384 + t * 2 + 1];
        p.out2[gr * 2]     = y0 + p.db2[0];
        p.out2[gr * 2 + 1] = y1 + p.db2[1];
      }
    }
  }
}

// =================================================================================================
extern "C" void kernel_launch(void* const* d_in, const int* in_sizes, int n_in,
                              void* d_out, int out_size, void* d_ws, size_t ws_size,
                              hipStream_t stream) {
  const void* grid_input    = d_in[0];
  const void* mesh_features = d_in[1];
  const void* edge_attr     = d_in[2];
  const void* g2m_w         = d_in[3];
  const void* m2g_w         = d_in[4];
  const int* edge_index     = (const int*)d_in[5];
  const int* g2m_i          = (const int*)d_in[6];
  const int* m2g_i          = (const int*)d_in[7];
  const void* grid_w1 = d_in[8];
  const void* grid_b1 = d_in[9];
  const void* grid_g  = d_in[10];
  const void* grid_be = d_in[11];
  const void* grid_w2 = d_in[12];
  const void* grid_b2 = d_in[13];
  const void* comb_w1 = d_in[14];
  const void* comb_b1 = d_in[15];
  const void* comb_g  = d_in[16];
  const void* comb_be = d_in[17];
  const void* comb_w2 = d_in[18];
  const void* comb_b2 = d_in[19];
  const void* edge_w  = d_in[20];
  const void* edge_b  = d_in[21];
  const void* edge_g  = d_in[22];
  const void* edge_be = d_in[23];
  const void* node_w1 = d_in[24];
  const void* node_b1 = d_in[25];
  const void* node_g  = d_in[26];
  const void* node_be = d_in[27];
  const void* node_w2 = d_in[28];
  const void* node_b2 = d_in[29];
  const void* dec_w1  = d_in[30];
  const void* dec_b1  = d_in[31];
  const void* dec_g   = d_in[32];
  const void* dec_be  = d_in[33];
  const void* dec_w2  = d_in[34];
  const void* dec_b2  = d_in[35];
  (void)in_sizes; (void)n_in; (void)out_size; (void)ws_size;

  const long BNG = (long)B_ * NG_;
  const long BNM = (long)B_ * NM_;

  char* ws = (char*)d_ws;
  size_t off = 0;
  auto al = [&](size_t n) -> char* {
    char* pp = ws + off;
    off += (n + 255) & ~(size_t)255;
    return pp;
  };

  int* dflag = (int*)al(256);
  u16* wt_grid_w2 = (u16*)al(256 * 256 * 2);
  u16* wt_comb_w1 = (u16*)al(256 * 288 * 2);
  u16* wt_comb_w2 = (u16*)al(256 * 256 * 2);
  u16* wt_dec_w1  = (u16*)al(256 * 256 * 2);
  u16* wt_etop    = (u16*)al((size_t)NL_ * 256 * 256 * 2);
  u16* wt_emid    = (u16*)al((size_t)NL_ * 256 * 256 * 2);
  u16* wt_node1   = (u16*)al((size_t)NL_ * 256 * 512 * 2);
  u16* wt_node2   = (u16*)al((size_t)NL_ * 256 * 256 * 2);
  float* c_gin  = (float*)al((size_t)BNG * 2 * 4);
  float* c_mf   = (float*)al((size_t)NM_ * 3 * 4);
  float* c_ea   = (float*)al((size_t)E_ * 4 * 4);
  float* c_g2mw = (float*)al((size_t)NM_ * 16 * 4);
  float* c_m2gw = (float*)al((size_t)NG_ * 4 * 4);
  float* varena = (float*)al(24576 * 4);
  float* gstats = (float*)al((size_t)BNG * 2 * 4);
  int* deg  = (int*)al((size_t)NM_ * 4);
  int* offb = (int*)al((size_t)(NM_ + 1) * 4);
  int* posb = (int*)al((size_t)NM_ * 4);
  int* ecsr = (int*)al((size_t)E_ * 4);
  int* srcs = (int*)al((size_t)E_ * 4);
  u16* eaW  = (u16*)al((size_t)E_ * 256 * 2);
  char* regA = al((size_t)BNM * 256 * 4);
  u16* gp_b   = (u16*)regA;
  u16* t2     = (u16*)regA;
  float* Uf   = (float*)regA;
  char* regB = al((size_t)BNM * 256 * 4);
  u16* pooled = (u16*)regB;
  float* agg  = (float*)regB;
  float* xf32 = (float*)al((size_t)BNM * 256 * 4);
  u16* xb16   = (u16*)al((size_t)BNM * 256 * 2);
  u16* Vh     = (u16*)al((size_t)BNM * 256 * 2);

  const int O_GB1 = 0, O_GG = 256, O_GBE = 512, O_GB2 = 768;
  const int O_CB1 = 1024, O_CG = 1280, O_CBE = 1536, O_CB2 = 1792;
  const int O_DB1 = 2048, O_DG = 2304, O_DBE = 2560, O_DB2 = 2816, O_DW2 = 2880;
  const int O_EB = 3584, O_EG = 5120, O_EBE = 6656;
  const int O_NB1 = 8192, O_NG = 9728, O_NBE = 11264, O_NB2 = 12800;
  const int O_GW1 = 14336;
  const int O_WBOT = 16384;

  detect_k<<<dim3(1), 64, 0, stream>>>((const u32*)grid_g, dflag);
  cvt_k<<<dim3((int)((BNG * 2 + 255) / 256)), 256, 0, stream>>>(grid_input, c_gin, BNG * 2, dflag);
  cvt_k<<<dim3((NM_ * 3 + 255) / 256), 256, 0, stream>>>(mesh_features, c_mf, (long)NM_ * 3, dflag);
  cvt_k<<<dim3((E_ * 4 + 255) / 256), 256, 0, stream>>>(edge_attr, c_ea, (long)E_ * 4, dflag);
  cvt_k<<<dim3((NM_ * 16 + 255) / 256), 256, 0, stream>>>(g2m_w, c_g2mw, (long)NM_ * 16, dflag);
  cvt_k<<<dim3((NG_ * 4 + 255) / 256), 256, 0, stream>>>(m2g_w, c_m2gw, (long)NG_ * 4, dflag);
  {
    CvtMany cm{};
    cm.dstbase = varena; cm.flag = dflag;
    int i = 0;
    auto add = [&](const void* s, long so, int o, int n) {
      cm.src[i] = s; cm.soff[i] = so; cm.off[i] = o; cm.n[i] = n; i++;
    };
    add(grid_b1, 0, O_GB1, 256); add(grid_g, 0, O_GG, 256); add(grid_be, 0, O_GBE, 256); add(grid_b2, 0, O_GB2, 256);
    add(comb_b1, 0, O_CB1, 256); add(comb_g, 0, O_CG, 256); add(comb_be, 0, O_CBE, 256); add(comb_b2, 0, O_CB2, 256);
    add(dec_b1, 0, O_DB1, 256);  add(dec_g, 0, O_DG, 256);  add(dec_be, 0, O_DBE, 256);  add(dec_b2, 0, O_DB2, 2);
    add(dec_w2, 0, O_DW2, 512);
    add(edge_b, 0, O_EB, NL_ * 256); add(edge_g, 0, O_EG, NL_ * 256); add(edge_be, 0, O_EBE, NL_ * 256);
    add(node_b1, 0, O_NB1, NL_ * 256); add(node_g, 0, O_NG, NL_ * 256); add(node_be, 0, O_NBE, NL_ * 256);
    add(node_b2, 0, O_NB2, NL_ * 256);
    add(grid_w1, 0, O_GW1, 512);
    for (int l = 0; l < NL_; l++)
      add(edge_w, (long)l * 516 * 256 + 512 * 256, O_WBOT + l * 1024, 1024);
    cm.cnt = i;
    cvt_many_k<<<dim3(6, cm.cnt), 256, 0, stream>>>(cm);
  }

  transpose_k<<<dim3(256, 1, 1), 256, 0, stream>>>(grid_w2, wt_grid_w2, 256, 256, 0, 0, 0, dflag);
  transpose_k<<<dim3(288, 1, 1), 256, 0, stream>>>(comb_w1, wt_comb_w1, 259, 288, 0, 0, 0, dflag);
  transpose_k<<<dim3(256, 1, 1), 256, 0, stream>>>(comb_w2, wt_comb_w2, 256, 256, 0, 0, 0, dflag);
  transpose_k<<<dim3(256, 1, 1), 256, 0, stream>>>(dec_w1,  wt_dec_w1,  256, 256, 0, 0, 0, dflag);
  transpose_k<<<dim3(256, 1, NL_), 256, 0, stream>>>(edge_w, wt_etop, 256, 256, (long)516 * 256, (long)256 * 256, 0, dflag);
  transpose_k<<<dim3(256, 1, NL_), 256, 0, stream>>>(edge_w, wt_emid, 256, 256, (long)516 * 256, (long)256 * 256, (long)256 * 256, dflag);
  transpose_k<<<dim3(512, 1, NL_), 256, 0, stream>>>(node_w1, wt_node1, 512, 512, (long)512 * 256, (long)256 * 512, 0, dflag);
  transpose_k<<<dim3(256, 1, NL_), 256, 0, stream>>>(node_w2, wt_node2, 256, 256, (long)256 * 256, (long)256 * 256, 0, dflag);

  // ---- CSR build (by dst) + CSR-ordered src gather ----
  zero_i32_k<<<dim3((NM_ + 255) / 256), 256, 0, stream>>>(deg, NM_);
  deg_count_k<<<dim3(E_ / 256), 256, 0, stream>>>(edge_index + E_, deg);
  scan_k<<<dim3(1), 256, 0, stream>>>(deg, offb, posb);
  csr_fill_k<<<dim3(E_ / 256), 256, 0, stream>>>(edge_index + E_, posb, ecsr);
  srcs_k<<<dim3(E_ / 256), 256, 0, stream>>>(edge_index, ecsr, srcs);

  grid_stats_k<<<dim3((int)(BNG / 4)), 256, 0, stream>>>(c_gin, varena + O_GW1, varena + O_GB1, gstats, (int)BNG);

  // ---- grid encoder + g2m pooling, streamed per batch ----
  for (int b = 0; b < B_; b++) {
    GemmP p{}; p.Wt = wt_grid_w2; p.bias = varena + O_GB2; p.Y = gp_b;
    p.gin = c_gin; p.gw1 = varena + O_GW1; p.gb1 = varena + O_GB1;
    p.gg = varena + O_GG; p.gbe = varena + O_GBE;
    p.stats = gstats; p.rowoff = (long)b * NG_;
    p.M = NG_; p.K = 256; p.Kpad = 256;
    gemm_k<A_GRID, E_STORE><<<dim3((NG_ + 63) / 64), 256, 0, stream>>>(p);
    g2m_b_k<<<dim3(NM_), 256, 0, stream>>>(gp_b, g2m_i, c_g2mw, pooled + (long)b * NM_ * 256);
  }

  // ---- comb MLP ----
  {
    GemmP p{}; p.A = pooled; p.mf = c_mf; p.Wt = wt_comb_w1; p.bias = varena + O_CB1;
    p.g = varena + O_CG; p.beta = varena + O_CBE; p.Y = t2; p.M = (int)BNM; p.K = 259; p.Kpad = 288;
    gemm_k<A_COMB, E_LN_STORE><<<dim3((int)((BNM + 63) / 64)), 256, 0, stream>>>(p);
  }
  const long n4 = BNM * 256 / 4;
  zero_f32_k<<<dim3((int)((n4 + 255) / 256)), 256, 0, stream>>>(xf32, n4);
  {
    GemmP p{}; p.A = t2; p.Wt = wt_comb_w2; p.bias = varena + O_CB2;
    p.xf32 = xf32; p.xb16 = xb16;
    p.M = (int)BNM; p.K = 256; p.Kpad = 256;
    gemm_k<A_DIRECT, E_RESID><<<dim3((int)((BNM + 63) / 64)), 256, 0, stream>>>(p);
  }

  // ---- message-passing layers ----
  for (int l = 0; l < NL_; l++) {
    eaw_k<<<dim3(E_ / 4), 256, 0, stream>>>(c_ea, ecsr, varena + O_WBOT + l * 1024,
                                            varena + O_EB + l * 256, eaW);
    {
      GemmP p{}; p.A = xb16;
      p.Wt = wt_etop + (size_t)l * 256 * 256;
      p.Wt2 = wt_emid + (size_t)l * 256 * 256;
      p.Yf = Uf; p.Y = Vh;
      p.M = (int)BNM; p.K = 256; p.Kpad = 256;
      gemm_k<A_DIRECT, E_STORE_UV><<<dim3((int)((BNM + 63) / 64), 2), 256, 0, stream>>>(p);
    }
    edge_combine_csr2_k<<<dim3((2 * NM_ + 3) / 4), 256, 0, stream>>>(
        Uf, Vh, eaW,
        varena + O_EG + l * 256, varena + O_EBE + l * 256,
        srcs, offb, agg);
    {
      GemmP p{}; p.Axh = xb16; p.Aagg = agg; p.Wt = wt_node1 + (size_t)l * 256 * 512;
      p.bias = varena + O_NB1 + l * 256; p.g = varena + O_NG + l * 256; p.beta = varena + O_NBE + l * 256;
      p.Y = t2; p.M = (int)BNM; p.K = 512; p.Kpad = 512;
      gemm_k<A_NODE1, E_LN_STORE><<<dim3((int)((BNM + 63) / 64)), 256, 0, stream>>>(p);
    }
    {
      GemmP p{}; p.A = t2; p.Wt = wt_node2 + (size_t)l * 256 * 256;
      p.bias = varena + O_NB2 + l * 256; p.xf32 = xf32; p.xb16 = xb16;
      p.M = (int)BNM; p.K = 256; p.Kpad = 256;
      gemm_k<A_DIRECT, E_RESID><<<dim3((int)((BNM + 63) / 64)), 256, 0, stream>>>(p);
    }
  }

  // ---- decoder: fused m2g gather staging, single launch; f32 output ----
  {
    GemmP p{}; p.Wt = wt_dec_w1; p.bias = varena + O_DB1;
    p.g = varena + O_DG; p.beta = varena + O_DBE;
    p.dw2 = varena + O_DW2; p.db2 = varena + O_DB2;
    p.out2 = (float*)d_out;
    p.xsh = xb16; p.m2gi = m2g_i; p.m2gw = c_m2gw;
    p.M = (int)BNG; p.K = 256; p.Kpad = 256;
    gemm_k<A_M2G, E_LN_DEC><<<dim3((int)((BNG + 63) / 64)), 256, 0, stream>>>(p);
  }
}

// Round 15
// 1736.656 us; speedup vs baseline: 1.0809x; 1.0241x over previous
//
#include <hip/hip_runtime.h>

using u16 = unsigned short;
using u32 = unsigned int;

typedef __attribute__((ext_vector_type(8))) short short8;
typedef __attribute__((ext_vector_type(4))) float floatx4;

#define B_  4
#define NG_ 40962
#define NM_ 10242
#define E_  65536
#define NL_ 6

__device__ __forceinline__ float bf2f(u16 u) {
  union { float f; u32 i; } x; x.i = ((u32)u) << 16; return x.f;
}
__device__ __forceinline__ u16 f2bf(float f) {
  union { float f; u32 i; } x; x.f = f;
  u32 i = x.i;
  u32 r = (i + 0x7FFFu + ((i >> 16) & 1u)) >> 16;
  return (u16)r;
}
__device__ __forceinline__ float silu_f(float v) {
  float c = fminf(fmaxf(v, -88.f), 88.f);
  return c / (1.f + __expf(-c));
}
__device__ __forceinline__ float silu_fast(float v) {
  return v / (1.f + __expf(-v));
}
__device__ __forceinline__ float satf(float v) {
  return fminf(fmaxf(v, -65504.f), 65504.f);
}
__device__ __forceinline__ float rdf(const void* p, long i, int flg) {
  return flg ? bf2f(((const u16*)p)[i]) : ((const float*)p)[i];
}

// ---------------- dtype detect ---------------------------------------------------------------
__global__ void detect_k(const u32* __restrict__ gg, int* __restrict__ flag) {
  if (threadIdx.x == 0) *flag = (gg[0] == 0x3F800000u) ? 0 : 1;
}

// ---------------- canonicalize one array to f32 ----------------------------------------------
__global__ __launch_bounds__(256) void cvt_k(const void* __restrict__ src, float* __restrict__ dst,
                                             long n, const int* __restrict__ flag) {
  int flg = *flag;
  long i = (long)blockIdx.x * 256 + threadIdx.x;
  if (i < n) dst[i] = rdf(src, i, flg);
}

// ---------------- canonicalize many small arrays ---------------------------------------------
struct CvtMany {
  const void* src[32];
  long soff[32];
  int off[32];
  int n[32];
  int cnt;
  float* dstbase;
  const int* flag;
};
__global__ __launch_bounds__(256) void cvt_many_k(CvtMany cm) {
  int e = blockIdx.y;
  if (e >= cm.cnt) return;
  int flg = *cm.flag;
  int i = blockIdx.x * 256 + threadIdx.x;
  if (i < cm.n[e]) cm.dstbase[cm.off[e] + i] = rdf(cm.src[e], cm.soff[e] + i, flg);
}

// ---------------- weight transpose -----------------------------------------------------------
__global__ void transpose_k(const void* __restrict__ src, u16* __restrict__ dst,
                            int K, int Kpad, long smat, long dmat, long soff,
                            const int* __restrict__ flag) {
  int flg = *flag;
  long l = blockIdx.z;
  int idx = blockIdx.x * 256 + threadIdx.x;
  int n = idx / Kpad;
  int k = idx - n * Kpad;
  if (n < 256)
    dst[l * dmat + (long)n * Kpad + k] =
        (k < K) ? f2bf(rdf(src, soff + l * smat + (long)k * 256 + n, flg)) : (u16)0;
}

// ---------------- zero helpers ---------------------------------------------------------------
__global__ __launch_bounds__(256) void zero_f32_k(float* __restrict__ p, long n4) {
  long i = (long)blockIdx.x * 256 + threadIdx.x;
  if (i < n4) ((float4*)p)[i] = (float4){0.f, 0.f, 0.f, 0.f};
}
__global__ __launch_bounds__(256) void zero_i32_k(int* __restrict__ p, int n) {
  int i = blockIdx.x * 256 + threadIdx.x;
  if (i < n) p[i] = 0;
}

// ---------------- CSR build (by destination) -------------------------------------------------
__global__ __launch_bounds__(256) void deg_count_k(const int* __restrict__ edst, int* __restrict__ deg) {
  int e = blockIdx.x * 256 + threadIdx.x;
  if (e < E_) atomicAdd(&deg[edst[e]], 1);
}
__global__ __launch_bounds__(256) void scan_k(const int* __restrict__ deg, int* __restrict__ off,
                                              int* __restrict__ pos) {
  __shared__ int tot[256];
  __shared__ int pre[257];
  const int CH = (NM_ + 255) / 256;
  int t = threadIdx.x;
  int base = t * CH;
  int s = 0;
  for (int i = 0; i < CH; i++) {
    int idx = base + i;
    if (idx < NM_) s += deg[idx];
  }
  tot[t] = s;
  __syncthreads();
  if (t == 0) {
    int acc = 0;
    for (int i = 0; i < 256; i++) { pre[i] = acc; acc += tot[i]; }
    pre[256] = acc;
  }
  __syncthreads();
  int acc = pre[t];
  for (int i = 0; i < CH; i++) {
    int idx = base + i;
    if (idx < NM_) { off[idx] = acc; pos[idx] = acc; acc += deg[idx]; }
  }
  if (t == 0) off[NM_] = pre[256];
}
__global__ __launch_bounds__(256) void csr_fill_k(const int* __restrict__ edst,
                                                  int* __restrict__ pos, int* __restrict__ ecsr) {
  int e = blockIdx.x * 256 + threadIdx.x;
  if (e < E_) {
    int p = atomicAdd(&pos[edst[e]], 1);
    ecsr[p] = e;
  }
}
__global__ __launch_bounds__(256) void srcs_k(const int* __restrict__ esrc,
                                              const int* __restrict__ ecsr, int* __restrict__ srcs) {
  int p = blockIdx.x * 256 + threadIdx.x;
  if (p < E_) srcs[p] = esrc[ecsr[p]];
}

// ---------------- per-layer eaW (4 edges per block) ------------------------------------------
__global__ __launch_bounds__(256) void eaw_k(const float* __restrict__ ea,
                                             const int* __restrict__ ecsr,
                                             const float* __restrict__ wbot,
                                             const float* __restrict__ bias,
                                             u16* __restrict__ eaW) {
  int c = threadIdx.x;
  float w0 = wbot[c], w1 = wbot[256 + c], w2 = wbot[512 + c], w3 = wbot[768 + c], bi = bias[c];
  int p0 = blockIdx.x * 4;
  #pragma unroll
  for (int r = 0; r < 4; r++) {
    int p = p0 + r;
    int e = ecsr[p];
    float4 v = *(const float4*)(ea + (long)e * 4);
    eaW[(long)p * 256 + c] = f2bf(v.x * w0 + v.y * w1 + v.z * w2 + v.w * w3 + bi);
  }
}

// ---------------- grid encoder LN stats ------------------------------------------------------
__global__ __launch_bounds__(256) void grid_stats_k(const float* __restrict__ gin,
                                                    const float* __restrict__ w1,
                                                    const float* __restrict__ b1,
                                                    float* __restrict__ stats, int M) {
  int row = blockIdx.x * 4 + (threadIdx.x >> 6);
  int lane = threadIdx.x & 63;
  if (row >= M) return;
  float in0 = gin[(long)row * 2], in1 = gin[(long)row * 2 + 1];
  float s = 0.f, s2 = 0.f;
  #pragma unroll
  for (int j = 0; j < 4; j++) {
    int c = lane * 4 + j;
    float x = in0 * w1[c] + in1 * w1[256 + c] + b1[c];
    s += x; s2 += x * x;
  }
  #pragma unroll
  for (int o = 1; o < 64; o <<= 1) { s += __shfl_xor(s, o); s2 += __shfl_xor(s2, o); }
  if (lane == 0) {
    float mu = s * (1.f / 256.f);
    float var = fmaxf(s2 * (1.f / 256.f) - mu * mu, 0.f);
    stats[row * 2] = mu;
    stats[row * 2 + 1] = rsqrtf(var + 1e-5f);
  }
}

// ---------------- g2m pooling (single batch) -------------------------------------------------
__global__ __launch_bounds__(256) void g2m_b_k(const u16* __restrict__ gpb, const int* __restrict__ idx,
                                               const float* __restrict__ wts, u16* __restrict__ outb) {
  int m = blockIdx.x, c = threadIdx.x;
  float a = 0.f;
  #pragma unroll 4
  for (int k = 0; k < 16; k++) {
    int gi = idx[m * 16 + k];
    a += wts[m * 16 + k] * bf2f(gpb[(long)gi * 256 + c]);
  }
  outb[(long)m * 256 + c] = f2bf(a);
}

// ---------------- edge combine (CSR): one wave per (node, batch-pair); all-bf16 streams ------
__global__ __launch_bounds__(256) void edge_combine_csr2_k(
    const u16* __restrict__ U, const u16* __restrict__ V,
    const u16* __restrict__ eaW,
    const float* __restrict__ g, const float* __restrict__ beta,
    const int* __restrict__ srcs, const int* __restrict__ off,
    u16* __restrict__ agg) {
  long gid = (long)blockIdx.x * 4 + (threadIdx.x >> 6);   // unit in [0, 2*NM)
  if (gid >= 2L * NM_) return;
  int lane = threadIdx.x & 63;
  int h = (int)(gid / NM_);
  int n = (int)(gid - (long)h * NM_);
  int b0 = 2 * h, b1 = 2 * h + 1;
  int c0 = lane * 4;

  union { uint2 u; u16 h4[4]; } uw0, uw1;
  uw0.u = *(const uint2*)(U + ((long)b0 * NM_ + n) * 256 + c0);
  uw1.u = *(const uint2*)(U + ((long)b1 * NM_ + n) * 256 + c0);
  float up0[4], up1[4], gc[4], bc[4];
  #pragma unroll
  for (int j = 0; j < 4; j++) {
    up0[j] = bf2f(uw0.h4[j]); up1[j] = bf2f(uw1.h4[j]);
    gc[j] = g[c0 + j]; bc[j] = beta[c0 + j];
  }

  float A0[4] = {0.f, 0.f, 0.f, 0.f};
  float A1[4] = {0.f, 0.f, 0.f, 0.f};
  const u16* Vb0 = V + (long)b0 * NM_ * 256;
  const u16* Vb1 = V + (long)b1 * NM_ * 256;
  int e0 = off[n], e1 = off[n + 1];
  for (int i = e0; i < e1; i++) {
    int sn = srcs[i];
    union { uint2 u; u16 h4[4]; } ew, v0, v1;
    ew.u = *(const uint2*)(eaW + (long)i * 256 + c0);
    v0.u = *(const uint2*)(Vb0 + (long)sn * 256 + c0);
    v1.u = *(const uint2*)(Vb1 + (long)sn * 256 + c0);
    float m0[4], m1[4];
    float s0 = 0.f, q0 = 0.f, s1 = 0.f, q1 = 0.f;
    #pragma unroll
    for (int j = 0; j < 4; j++) {
      float e_ = bf2f(ew.h4[j]);
      float a = up0[j] + bf2f(v0.h4[j]) + e_;
      float b = up1[j] + bf2f(v1.h4[j]) + e_;
      m0[j] = a; m1[j] = b;
      s0 += a; q0 += a * a;
      s1 += b; q1 += b * b;
    }
    #pragma unroll
    for (int o = 1; o < 64; o <<= 1) {
      s0 += __shfl_xor(s0, o); q0 += __shfl_xor(q0, o);
      s1 += __shfl_xor(s1, o); q1 += __shfl_xor(q1, o);
    }
    float mu0 = s0 * (1.f / 256.f);
    float rs0 = rsqrtf(fmaxf(q0 * (1.f / 256.f) - mu0 * mu0, 0.f) + 1e-5f);
    float mu1 = s1 * (1.f / 256.f);
    float rs1 = rsqrtf(fmaxf(q1 * (1.f / 256.f) - mu1 * mu1, 0.f) + 1e-5f);
    #pragma unroll
    for (int j = 0; j < 4; j++) {
      A0[j] += silu_fast((m0[j] - mu0) * rs0 * gc[j] + bc[j]);
      A1[j] += silu_fast((m1[j] - mu1) * rs1 * gc[j] + bc[j]);
    }
  }
  union { uint2 u; u16 h4[4]; } o0, o1;
  #pragma unroll
  for (int j = 0; j < 4; j++) { o0.h4[j] = f2bf(A0[j]); o1.h4[j] = f2bf(A1[j]); }
  *(uint2*)(agg + ((long)b0 * NM_ + n) * 256 + c0) = o0.u;
  *(uint2*)(agg + ((long)b1 * NM_ + n) * 256 + c0) = o1.u;
}

// ---------------- the MFMA GEMM template -----------------------------------------------------
enum { A_DIRECT = 0, A_NODE1 = 2, A_GRID = 3, A_COMB = 4, A_M2G = 5 };
enum { E_STORE = 0, E_LN_STORE = 3, E_RESID = 4, E_LN_DEC = 5, E_STORE_UV = 6 };

struct GemmP {
  const u16* A;
  const u16* Axh;      // node1: x bf16 shadow
  const u16* Aaggh;    // node1: agg bf16
  const u16* Wt;
  const u16* Wt2;      // E_STORE_UV: second weight set (V)
  const float* bias;
  const float* g;
  const float* beta;
  u16* Y;
  u16* Y2;             // E_STORE_UV: V output
  float* xf32;
  u16* xb16;
  const float* mf;
  const float* dw2;
  const float* db2;
  float* out2;
  const float* gin;
  const float* gw1;
  const float* gb1;
  const float* gg;
  const float* gbe;
  const float* stats;
  const u16* xsh;
  const int* m2gi;
  const float* m2gw;
  long rowoff;
  int M, K, Kpad;
};

template <int AM, int EM>
__global__ __launch_bounds__(256, 2) void gemm_k(GemmP p) {
  __shared__ __align__(16) u16 Asm[64 * 40];
  __shared__ __align__(16) u16 Bsm[256 * 40];
  __shared__ float red[4 * 64 * 2];
  __shared__ float stats_sm[64][2];

  const int t = threadIdx.x;
  const int lane = t & 63, w = t >> 6;
  const int l15 = lane & 15, q = lane >> 4;
  const long blk = blockIdx.x;

  const int lr = t >> 2;
  const int c8 = (t & 3) * 8;
  const long gr_s = blk * 64 + lr;
  const bool rowv = (gr_s < p.M);

  const u16* Wt = p.Wt;
  if (EM == E_STORE_UV && blockIdx.y == 1) Wt = p.Wt2;

  int cmn = 0;
  if (AM == A_COMB) cmn = (int)(gr_s % NM_);
  float gin0 = 0.f, gin1 = 0.f, gmu = 0.f, grs = 0.f;
  if (AM == A_GRID && rowv) {
    long grow = p.rowoff + gr_s;
    gin0 = p.gin[grow * 2];
    gin1 = p.gin[grow * 2 + 1];
    gmu = p.stats[grow * 2];
    grs = p.stats[grow * 2 + 1];
  }
  long xrow[4];
  float gw4[4];
  if (AM == A_M2G && rowv) {
    int b = (int)(gr_s / NG_);
    int gn = (int)(gr_s - (long)b * NG_);
    #pragma unroll
    for (int s = 0; s < 4; s++) {
      xrow[s] = ((long)(b * NM_ + p.m2gi[gn * 4 + s])) * 256;
      gw4[s] = p.m2gw[gn * 4 + s];
    }
  }

  floatx4 acc[4][4];
  #pragma unroll
  for (int i = 0; i < 4; i++)
    #pragma unroll
    for (int j = 0; j < 4; j++) acc[i][j] = (floatx4){0.f, 0.f, 0.f, 0.f};

  const int nk = p.Kpad >> 5;
  for (int ks = 0; ks < nk; ks++) {
    const int k0 = ks << 5;
    const int kc = k0 + c8;

    union { uint4 v; u16 s[8]; } av;
    av.v = (uint4){0u, 0u, 0u, 0u};
    if (AM == A_DIRECT) {
      if (rowv) av.v = *(const uint4*)(p.A + gr_s * (long)p.K + kc);
    } else if (AM == A_NODE1) {
      if (rowv) {
        if (kc < 256) av.v = *(const uint4*)(p.Axh + gr_s * 256 + kc);
        else          av.v = *(const uint4*)(p.Aaggh + gr_s * 256 + (kc - 256));
      }
    } else if (AM == A_COMB) {
      if (rowv) {
        if (kc < 256) {
          av.v = *(const uint4*)(p.A + gr_s * 256 + kc);
        } else {
          #pragma unroll
          for (int j = 0; j < 8; j++) {
            int c = kc - 256 + j;
            av.s[j] = (c < 3) ? f2bf(p.mf[(long)cmn * 3 + c]) : (u16)0;
          }
        }
      }
    } else if (AM == A_M2G) {
      if (rowv) {
        float a8[8] = {0.f, 0.f, 0.f, 0.f, 0.f, 0.f, 0.f, 0.f};
        #pragma unroll
        for (int s = 0; s < 4; s++) {
          union { uint4 v; u16 h[8]; } xv;
          xv.v = *(const uint4*)(p.xsh + xrow[s] + kc);
          #pragma unroll
          for (int j = 0; j < 8; j++) a8[j] += gw4[s] * bf2f(xv.h[j]);
        }
        #pragma unroll
        for (int j = 0; j < 8; j++) av.s[j] = f2bf(a8[j]);
      }
    } else { // A_GRID
      if (rowv) {
        #pragma unroll
        for (int j = 0; j < 8; j++) {
          int c = kc + j;
          float tv = gin0 * p.gw1[c] + gin1 * p.gw1[256 + c] + p.gb1[c];
          float v = (tv - gmu) * grs * p.gg[c] + p.gbe[c];
          av.s[j] = f2bf(silu_f(v));
        }
      }
    }

    __syncthreads();
    *(uint4*)(Asm + lr * 40 + c8) = av.v;
    {
      const uint4* wp = (const uint4*)(Wt + (long)t * p.Kpad + k0);
      uint4 b0 = wp[0], b1 = wp[1], b2 = wp[2], b3 = wp[3];
      uint4* bs = (uint4*)(Bsm + t * 40);
      bs[0] = b0; bs[1] = b1; bs[2] = b2; bs[3] = b3;
    }
    __syncthreads();

    short8 af[4], bf[4];
    #pragma unroll
    for (int i = 0; i < 4; i++)
      af[i] = *(const short8*)(Asm + (i * 16 + l15) * 40 + q * 8);
    #pragma unroll
    for (int j = 0; j < 4; j++)
      bf[j] = *(const short8*)(Bsm + (w * 64 + j * 16 + l15) * 40 + q * 8);
    #pragma unroll
    for (int i = 0; i < 4; i++)
      #pragma unroll
      for (int j = 0; j < 4; j++)
        acc[i][j] = __builtin_amdgcn_mfma_f32_16x16x32_bf16(af[i], bf[j], acc[i][j], 0, 0, 0);
  }

  // ================= epilogue =================
  const int colb = w * 64 + l15;
  float bcol[4];
  #pragma unroll
  for (int j = 0; j < 4; j++) bcol[j] = p.bias ? p.bias[colb + j * 16] : 0.f;

  if (EM == E_STORE || EM == E_RESID || EM == E_STORE_UV) {
    u16* Yuv = p.Y;
    if (EM == E_STORE_UV && blockIdx.y == 1) Yuv = p.Y2;
    #pragma unroll
    for (int i = 0; i < 4; i++) {
      #pragma unroll
      for (int r = 0; r < 4; r++) {
        long gr = blk * 64 + i * 16 + q * 4 + r;
        if (gr >= p.M) continue;
        long rowo = gr * 256 + colb;
        #pragma unroll
        for (int j = 0; j < 4; j++) {
          float v = acc[i][j][r] + bcol[j];
          long o = rowo + j * 16;
          if (EM == E_STORE) {
            p.Y[o] = f2bf(v);
          } else if (EM == E_STORE_UV) {
            Yuv[o] = f2bf(v);
          } else {
            float nv = satf(p.xf32[o] + v);
            p.xf32[o] = nv;
            p.xb16[o] = f2bf(nv);
          }
        }
      }
    }
    return;
  }

  // ---- LN: bias + row sums via 16-lane shuffle; cross-wave via 2 KB red ----
  #pragma unroll
  for (int i = 0; i < 4; i++) {
    #pragma unroll
    for (int r = 0; r < 4; r++) {
      float s = 0.f, s2 = 0.f;
      #pragma unroll
      for (int j = 0; j < 4; j++) {
        float v = satf(acc[i][j][r] + bcol[j]);
        acc[i][j][r] = v;
        s += v; s2 += v * v;
      }
      #pragma unroll
      for (int o = 1; o < 16; o <<= 1) { s += __shfl_xor(s, o); s2 += __shfl_xor(s2, o); }
      if (l15 == 0) {
        int ml = i * 16 + q * 4 + r;
        red[w * 128 + ml * 2]     = s;
        red[w * 128 + ml * 2 + 1] = s2;
      }
    }
  }
  __syncthreads();

  if (t < 64) {
    float s  = red[t * 2]     + red[128 + t * 2]     + red[256 + t * 2]     + red[384 + t * 2];
    float s2 = red[t * 2 + 1] + red[128 + t * 2 + 1] + red[256 + t * 2 + 1] + red[384 + t * 2 + 1];
    float mu = s * (1.f / 256.f);
    float var = fmaxf(s2 * (1.f / 256.f) - mu * mu, 0.f);
    stats_sm[t][0] = mu;
    stats_sm[t][1] = rsqrtf(var + 1e-5f);
  }
  __syncthreads();

  float gcol[4], becol[4];
  #pragma unroll
  for (int j = 0; j < 4; j++) { gcol[j] = p.g[colb + j * 16]; becol[j] = p.beta[colb + j * 16]; }

  if (EM == E_LN_STORE) {
    #pragma unroll
    for (int i = 0; i < 4; i++) {
      #pragma unroll
      for (int r = 0; r < 4; r++) {
        int ml = i * 16 + q * 4 + r;
        long gr = blk * 64 + ml;
        if (gr >= p.M) continue;
        float mu = stats_sm[ml][0], rs = stats_sm[ml][1];
        long rowo = gr * 256 + colb;
        #pragma unroll
        for (int j = 0; j < 4; j++) {
          float v = (acc[i][j][r] - mu) * rs * gcol[j] + becol[j];
          p.Y[rowo + j * 16] = f2bf(silu_f(v));
        }
      }
    }
  } else { // E_LN_DEC
    #pragma unroll
    for (int i = 0; i < 4; i++) {
      #pragma unroll
      for (int r = 0; r < 4; r++) {
        int ml = i * 16 + q * 4 + r;
        float mu = stats_sm[ml][0], rs = stats_sm[ml][1];
        float d0 = 0.f, d1 = 0.f;
        #pragma unroll
        for (int j = 0; j < 4; j++) {
          int col = colb + j * 16;
          float v = silu_f((acc[i][j][r] - mu) * rs * gcol[j] + becol[j]);
          d0 += v * p.dw2[col * 2];
          d1 += v * p.dw2[col * 2 + 1];
        }
        #pragma unroll
        for (int o = 1; o < 16; o <<= 1) { d0 += __shfl_xor(d0, o); d1 += __shfl_xor(d1, o); }
        if (l15 == 0) {
          red[w * 128 + ml * 2]     = d0;
          red[w * 128 + ml * 2 + 1] = d1;
        }
      }
    }
    __syncthreads();
    if (t < 64) {
      long gr = blk * 64 + t;
      if (gr < p.M) {
        float y0 = red[t * 2]     + red[128 + t * 2]     + red[256 + t * 2]     + red[384 + t * 2];
        float y1 = red[t * 2 + 1] + red[128 + t * 2 + 1] + red[256 + t * 2 + 1] + red[384 + t * 2 + 1];
        p.out2[gr * 2]     = y0 + p.db2[0];
        p.out2[gr * 2 + 1] = y1 + p.db2[1];
      }
    }
  }
}

// =================================================================================================
extern "C" void kernel_launch(void* const* d_in, const int* in_sizes, int n_in,
                              void* d_out, int out_size, void* d_ws, size_t ws_size,
                              hipStream_t stream) {
  const void* grid_input    = d_in[0];
  const void* mesh_features = d_in[1];
  const void* edge_attr     = d_in[2];
  const void* g2m_w         = d_in[3];
  const void* m2g_w         = d_in[4];
  const int* edge_index     = (const int*)d_in[5];
  const int* g2m_i          = (const int*)d_in[6];
  const int* m2g_i          = (const int*)d_in[7];
  const void* grid_w1 = d_in[8];
  const void* grid_b1 = d_in[9];
  const void* grid_g  = d_in[10];
  const void* grid_be = d_in[11];
  const void* grid_w2 = d_in[12];
  const void* grid_b2 = d_in[13];
  const void* comb_w1 = d_in[14];
  const void* comb_b1 = d_in[15];
  const void* comb_g  = d_in[16];
  const void* comb_be = d_in[17];
  const void* comb_w2 = d_in[18];
  const void* comb_b2 = d_in[19];
  const void* edge_w  = d_in[20];
  const void* edge_b  = d_in[21];
  const void* edge_g  = d_in[22];
  const void* edge_be = d_in[23];
  const void* node_w1 = d_in[24];
  const void* node_b1 = d_in[25];
  const void* node_g  = d_in[26];
  const void* node_be = d_in[27];
  const void* node_w2 = d_in[28];
  const void* node_b2 = d_in[29];
  const void* dec_w1  = d_in[30];
  const void* dec_b1  = d_in[31];
  const void* dec_g   = d_in[32];
  const void* dec_be  = d_in[33];
  const void* dec_w2  = d_in[34];
  const void* dec_b2  = d_in[35];
  (void)in_sizes; (void)n_in; (void)out_size; (void)ws_size;

  const long BNG = (long)B_ * NG_;
  const long BNM = (long)B_ * NM_;

  char* ws = (char*)d_ws;
  size_t off = 0;
  auto al = [&](size_t n) -> char* {
    char* pp = ws + off;
    off += (n + 255) & ~(size_t)255;
    return pp;
  };

  int* dflag = (int*)al(256);
  u16* wt_grid_w2 = (u16*)al(256 * 256 * 2);
  u16* wt_comb_w1 = (u16*)al(256 * 288 * 2);
  u16* wt_comb_w2 = (u16*)al(256 * 256 * 2);
  u16* wt_dec_w1  = (u16*)al(256 * 256 * 2);
  u16* wt_etop    = (u16*)al((size_t)NL_ * 256 * 256 * 2);
  u16* wt_emid    = (u16*)al((size_t)NL_ * 256 * 256 * 2);
  u16* wt_node1   = (u16*)al((size_t)NL_ * 256 * 512 * 2);
  u16* wt_node2   = (u16*)al((size_t)NL_ * 256 * 256 * 2);
  float* c_gin  = (float*)al((size_t)BNG * 2 * 4);
  float* c_mf   = (float*)al((size_t)NM_ * 3 * 4);
  float* c_ea   = (float*)al((size_t)E_ * 4 * 4);
  float* c_g2mw = (float*)al((size_t)NM_ * 16 * 4);
  float* c_m2gw = (float*)al((size_t)NG_ * 4 * 4);
  float* varena = (float*)al(24576 * 4);
  float* gstats = (float*)al((size_t)BNG * 2 * 4);
  int* deg  = (int*)al((size_t)NM_ * 4);
  int* offb = (int*)al((size_t)(NM_ + 1) * 4);
  int* posb = (int*)al((size_t)NM_ * 4);
  int* ecsr = (int*)al((size_t)E_ * 4);
  int* srcs = (int*)al((size_t)E_ * 4);
  u16* eaW  = (u16*)al((size_t)E_ * 256 * 2);
  // region A (21 MB bf16): gp_b / t2 / Uh (disjoint lifetimes)
  char* regA = al((size_t)BNM * 256 * 2);
  u16* gp_b = (u16*)regA;
  u16* t2   = (u16*)regA;
  u16* Uh   = (u16*)regA;
  // region B (21 MB bf16): pooled then agg (bf16)
  char* regB = al((size_t)BNM * 256 * 2);
  u16* pooled = (u16*)regB;
  u16* aggh   = (u16*)regB;
  float* xf32 = (float*)al((size_t)BNM * 256 * 4);
  u16* xb16   = (u16*)al((size_t)BNM * 256 * 2);
  u16* Vh     = (u16*)al((size_t)BNM * 256 * 2);

  const int O_GB1 = 0, O_GG = 256, O_GBE = 512, O_GB2 = 768;
  const int O_CB1 = 1024, O_CG = 1280, O_CBE = 1536, O_CB2 = 1792;
  const int O_DB1 = 2048, O_DG = 2304, O_DBE = 2560, O_DB2 = 2816, O_DW2 = 2880;
  const int O_EB = 3584, O_EG = 5120, O_EBE = 6656;
  const int O_NB1 = 8192, O_NG = 9728, O_NBE = 11264, O_NB2 = 12800;
  const int O_GW1 = 14336;
  const int O_WBOT = 16384;

  detect_k<<<dim3(1), 64, 0, stream>>>((const u32*)grid_g, dflag);
  cvt_k<<<dim3((int)((BNG * 2 + 255) / 256)), 256, 0, stream>>>(grid_input, c_gin, BNG * 2, dflag);
  cvt_k<<<dim3((NM_ * 3 + 255) / 256), 256, 0, stream>>>(mesh_features, c_mf, (long)NM_ * 3, dflag);
  cvt_k<<<dim3((E_ * 4 + 255) / 256), 256, 0, stream>>>(edge_attr, c_ea, (long)E_ * 4, dflag);
  cvt_k<<<dim3((NM_ * 16 + 255) / 256), 256, 0, stream>>>(g2m_w, c_g2mw, (long)NM_ * 16, dflag);
  cvt_k<<<dim3((NG_ * 4 + 255) / 256), 256, 0, stream>>>(m2g_w, c_m2gw, (long)NG_ * 4, dflag);
  {
    CvtMany cm{};
    cm.dstbase = varena; cm.flag = dflag;
    int i = 0;
    auto add = [&](const void* s, long so, int o, int n) {
      cm.src[i] = s; cm.soff[i] = so; cm.off[i] = o; cm.n[i] = n; i++;
    };
    add(grid_b1, 0, O_GB1, 256); add(grid_g, 0, O_GG, 256); add(grid_be, 0, O_GBE, 256); add(grid_b2, 0, O_GB2, 256);
    add(comb_b1, 0, O_CB1, 256); add(comb_g, 0, O_CG, 256); add(comb_be, 0, O_CBE, 256); add(comb_b2, 0, O_CB2, 256);
    add(dec_b1, 0, O_DB1, 256);  add(dec_g, 0, O_DG, 256);  add(dec_be, 0, O_DBE, 256);  add(dec_b2, 0, O_DB2, 2);
    add(dec_w2, 0, O_DW2, 512);
    add(edge_b, 0, O_EB, NL_ * 256); add(edge_g, 0, O_EG, NL_ * 256); add(edge_be, 0, O_EBE, NL_ * 256);
    add(node_b1, 0, O_NB1, NL_ * 256); add(node_g, 0, O_NG, NL_ * 256); add(node_be, 0, O_NBE, NL_ * 256);
    add(node_b2, 0, O_NB2, NL_ * 256);
    add(grid_w1, 0, O_GW1, 512);
    for (int l = 0; l < NL_; l++)
      add(edge_w, (long)l * 516 * 256 + 512 * 256, O_WBOT + l * 1024, 1024);
    cm.cnt = i;
    cvt_many_k<<<dim3(6, cm.cnt), 256, 0, stream>>>(cm);
  }

  transpose_k<<<dim3(256, 1, 1), 256, 0, stream>>>(grid_w2, wt_grid_w2, 256, 256, 0, 0, 0, dflag);
  transpose_k<<<dim3(288, 1, 1), 256, 0, stream>>>(comb_w1, wt_comb_w1, 259, 288, 0, 0, 0, dflag);
  transpose_k<<<dim3(256, 1, 1), 256, 0, stream>>>(comb_w2, wt_comb_w2, 256, 256, 0, 0, 0, dflag);
  transpose_k<<<dim3(256, 1, 1), 256, 0, stream>>>(dec_w1,  wt_dec_w1,  256, 256, 0, 0, 0, dflag);
  transpose_k<<<dim3(256, 1, NL_), 256, 0, stream>>>(edge_w, wt_etop, 256, 256, (long)516 * 256, (long)256 * 256, 0, dflag);
  transpose_k<<<dim3(256, 1, NL_), 256, 0, stream>>>(edge_w, wt_emid, 256, 256, (long)516 * 256, (long)256 * 256, (long)256 * 256, dflag);
  transpose_k<<<dim3(512, 1, NL_), 256, 0, stream>>>(node_w1, wt_node1, 512, 512, (long)512 * 256, (long)256 * 512, 0, dflag);
  transpose_k<<<dim3(256, 1, NL_), 256, 0, stream>>>(node_w2, wt_node2, 256, 256, (long)256 * 256, (long)256 * 256, 0, dflag);

  // ---- CSR build (by dst) + CSR-ordered src gather ----
  zero_i32_k<<<dim3((NM_ + 255) / 256), 256, 0, stream>>>(deg, NM_);
  deg_count_k<<<dim3(E_ / 256), 256, 0, stream>>>(edge_index + E_, deg);
  scan_k<<<dim3(1), 256, 0, stream>>>(deg, offb, posb);
  csr_fill_k<<<dim3(E_ / 256), 256, 0, stream>>>(edge_index + E_, posb, ecsr);
  srcs_k<<<dim3(E_ / 256), 256, 0, stream>>>(edge_index, ecsr, srcs);

  grid_stats_k<<<dim3((int)(BNG / 4)), 256, 0, stream>>>(c_gin, varena + O_GW1, varena + O_GB1, gstats, (int)BNG);

  // ---- grid encoder + g2m pooling, streamed per batch ----
  for (int b = 0; b < B_; b++) {
    GemmP p{}; p.Wt = wt_grid_w2; p.bias = varena + O_GB2; p.Y = gp_b;
    p.gin = c_gin; p.gw1 = varena + O_GW1; p.gb1 = varena + O_GB1;
    p.gg = varena + O_GG; p.gbe = varena + O_GBE;
    p.stats = gstats; p.rowoff = (long)b * NG_;
    p.M = NG_; p.K = 256; p.Kpad = 256;
    gemm_k<A_GRID, E_STORE><<<dim3((NG_ + 63) / 64), 256, 0, stream>>>(p);
    g2m_b_k<<<dim3(NM_), 256, 0, stream>>>(gp_b, g2m_i, c_g2mw, pooled + (long)b * NM_ * 256);
  }

  // ---- comb MLP ----
  {
    GemmP p{}; p.A = pooled; p.mf = c_mf; p.Wt = wt_comb_w1; p.bias = varena + O_CB1;
    p.g = varena + O_CG; p.beta = varena + O_CBE; p.Y = t2; p.M = (int)BNM; p.K = 259; p.Kpad = 288;
    gemm_k<A_COMB, E_LN_STORE><<<dim3((int)((BNM + 63) / 64)), 256, 0, stream>>>(p);
  }
  const long n4 = BNM * 256 / 4;
  zero_f32_k<<<dim3((int)((n4 + 255) / 256)), 256, 0, stream>>>(xf32, n4);
  {
    GemmP p{}; p.A = t2; p.Wt = wt_comb_w2; p.bias = varena + O_CB2;
    p.xf32 = xf32; p.xb16 = xb16;
    p.M = (int)BNM; p.K = 256; p.Kpad = 256;
    gemm_k<A_DIRECT, E_RESID><<<dim3((int)((BNM + 63) / 64)), 256, 0, stream>>>(p);
  }

  // ---- message-passing layers ----
  for (int l = 0; l < NL_; l++) {
    eaw_k<<<dim3(E_ / 4), 256, 0, stream>>>(c_ea, ecsr, varena + O_WBOT + l * 1024,
                                            varena + O_EB + l * 256, eaW);
    {
      GemmP p{}; p.A = xb16;
      p.Wt = wt_etop + (size_t)l * 256 * 256;
      p.Wt2 = wt_emid + (size_t)l * 256 * 256;
      p.Y = Uh; p.Y2 = Vh;
      p.M = (int)BNM; p.K = 256; p.Kpad = 256;
      gemm_k<A_DIRECT, E_STORE_UV><<<dim3((int)((BNM + 63) / 64), 2), 256, 0, stream>>>(p);
    }
    edge_combine_csr2_k<<<dim3((2 * NM_ + 3) / 4), 256, 0, stream>>>(
        Uh, Vh, eaW,
        varena + O_EG + l * 256, varena + O_EBE + l * 256,
        srcs, offb, aggh);
    {
      GemmP p{}; p.Axh = xb16; p.Aaggh = aggh; p.Wt = wt_node1 + (size_t)l * 256 * 512;
      p.bias = varena + O_NB1 + l * 256; p.g = varena + O_NG + l * 256; p.beta = varena + O_NBE + l * 256;
      p.Y = t2; p.M = (int)BNM; p.K = 512; p.Kpad = 512;
      gemm_k<A_NODE1, E_LN_STORE><<<dim3((int)((BNM + 63) / 64)), 256, 0, stream>>>(p);
    }
    {
      GemmP p{}; p.A = t2; p.Wt = wt_node2 + (size_t)l * 256 * 256;
      p.bias = varena + O_NB2 + l * 256; p.xf32 = xf32; p.xb16 = xb16;
      p.M = (int)BNM; p.K = 256; p.Kpad = 256;
      gemm_k<A_DIRECT, E_RESID><<<dim3((int)((BNM + 63) / 64)), 256, 0, stream>>>(p);
    }
  }

  // ---- decoder: fused m2g gather staging, single launch; f32 output ----
  {
    GemmP p{}; p.Wt = wt_dec_w1; p.bias = varena + O_DB1;
    p.g = varena + O_DG; p.beta = varena + O_DBE;
    p.dw2 = varena + O_DW2; p.db2 = varena + O_DB2;
    p.out2 = (float*)d_out;
    p.xsh = xb16; p.m2gi = m2g_i; p.m2gw = c_m2gw;
    p.M = (int)BNG; p.K = 256; p.Kpad = 256;
    gemm_k<A_M2G, E_LN_DEC><<<dim3((int)((BNG + 63) / 64)), 256, 0, stream>>>(p);
  }
}